// Round 11
// baseline (293.873 us; speedup 1.0000x reference)
//
#include <hip/hip_runtime.h>
#include <hip/hip_bf16.h>
#include <math.h>

// Problem constants
#define BB 4
#define CC 256
#define NN 4096          // H*W
#define EE 96
#define NTOT (BB*NN)     // 16384 rows

typedef __attribute__((ext_vector_type(8))) short bf16x8;
typedef __attribute__((ext_vector_type(4))) float f32x4;

// Branch-free RNE fp32->bf16 (bit-identical to __float2bfloat16 for finite
// inputs; all values converted in this pipeline are finite). Saves the
// NaN-check chain (~5 VALU) per convert.
__device__ __forceinline__ short f2bf(float x) {
    unsigned int u;
    __builtin_memcpy(&u, &x, 4);
    u += 0x7FFFu + ((u >> 16) & 1u);
    return (short)(u >> 16);
}
__device__ __forceinline__ float bf2f(short s) {
    unsigned int u = ((unsigned int)(unsigned short)s) << 16;
    float f;
    __builtin_memcpy(&f, &u, 4);
    return f;
}
__device__ __forceinline__ float gelu_exact(float v) {
    return 0.5f * v * (1.0f + erff(v * 0.70710678118654752f));
}
// async global->LDS, 16B per lane; LDS dest = uniform base + lane*16
__device__ __forceinline__ void gld16(void* lds, const void* g) {
    __builtin_amdgcn_global_load_lds(
        (const __attribute__((address_space(1))) unsigned int*)g,
        (__attribute__((address_space(3))) unsigned int*)lds, 16, 0, 0);
}

// Weight arena offsets (shorts). wg split into 256-stride matrix + last col.
#define OFF_WQ  0
#define OFF_WK  24576
#define OFF_WV  49152
#define OFF_WO  114688
#define OFF_WD1 180224
#define OFF_WD2 311296
#define OFF_WG  376832
#define OFF_WGL 442368
#define W16_TOTAL 442624

// ---------------------------------------------------------------------------
// Kernel 0: weight fp32 -> bf16 converter. v2: 4 elements/thread + short4
// store (442624 = 4*110656 exactly; grid 433).
// ---------------------------------------------------------------------------
__global__ void wconv_kernel(const float* __restrict__ wq, const float* __restrict__ wk,
                             const float* __restrict__ wv, const float* __restrict__ wo,
                             const float* __restrict__ wd1, const float* __restrict__ wd2,
                             const float* __restrict__ wg, short* __restrict__ W16) {
    int i0 = (blockIdx.x * 256 + threadIdx.x) * 4;
    if (i0 >= W16_TOTAL) return;
    short4 o;
    #pragma unroll
    for (int j = 0; j < 4; ++j) {
        int i = i0 + j;
        float v;
        if      (i < OFF_WK)  v = wq[i];
        else if (i < OFF_WV)  v = wk[i - OFF_WK];
        else if (i < OFF_WO)  v = wv[i - OFF_WV];
        else if (i < OFF_WD1) v = wo[i - OFF_WO];
        else if (i < OFF_WD2) v = wd1[i - OFF_WD1];
        else if (i < OFF_WG)  v = wd2[i - OFF_WD2];
        else if (i < OFF_WGL) { int l = i - OFF_WG; v = wg[(l >> 8) * 257 + (l & 255)]; }
        else                  v = wg[(i - OFF_WGL) * 257 + 256];
        ((short*)&o)[j] = f2bf(v);
    }
    *(short4*)&W16[i0] = o;
}

// ---------------------------------------------------------------------------
// Kernel 1: fused LayerNorm + Q/K/V projections. v3 kept (16 rows/block,
// grid 1024, 4 blocks/CU, wave-specialized proj, LDS-resident A-frags,
// lgkm-only mid barriers).
// ---------------------------------------------------------------------------
__global__ __launch_bounds__(256) void lnproj_kernel(
    const float* __restrict__ x, const float* __restrict__ gamma,
    const float* __restrict__ beta, const short* __restrict__ W16,
    const float* __restrict__ mask, const float* __restrict__ w_qm,
    short* __restrict__ Xt16, short* __restrict__ Xn16,
    short* __restrict__ Q16, short* __restrict__ K16,
    short* __restrict__ V16t)
{
    __shared__ char ldsbuf[17408];            // fp32 tile 256x17 | later Vt 256x24 b16
    float* tile = (float*)ldsbuf;
    short* Vt   = (short*)ldsbuf;
    __shared__ short Xn_lds[16 * 264];        // proj A-frags (normed)
    __shared__ short Xt_lds[16 * 264];        // proj A-frags (raw x)
    __shared__ float psum[16][16], psq[16][16];
    __shared__ float mu_s[16], rs_s[16];
    __shared__ float gs[256], bs[256];

    const int tid = threadIdx.x;
    const int w = tid >> 6, lane = tid & 63, ln = lane & 15, quad = lane >> 4;
    const int b  = blockIdx.x >> 8;
    const int p0 = (blockIdx.x & 255) * 16;
    const int m0 = blockIdx.x * 16;           // global row base (= b*NN + p0)
    const float* xb = x + (size_t)b * CC * NN;

    // ---------------- ln phase ----------------
    gs[tid] = gamma[tid];
    bs[tid] = beta[tid];
    #pragma unroll
    for (int i = 0; i < 4; ++i) {
        int idx = tid + i * 256;
        int c = idx >> 2, p4 = (idx & 3) * 4;
        float4 v = *(const float4*)&xb[(size_t)c * NN + p0 + p4];
        tile[c * 17 + p4]     = v.x;
        tile[c * 17 + p4 + 1] = v.y;
        tile[c * 17 + p4 + 2] = v.z;
        tile[c * 17 + p4 + 3] = v.w;
    }
    __syncthreads();
    {
        int col = tid & 15, part = tid >> 4;   // 16 parts x 16 positions
        float s = 0.f, sq = 0.f;
        for (int r = part * 16; r < part * 16 + 16; ++r) {
            float v = tile[r * 17 + col];
            s += v; sq += v * v;
        }
        psum[part][col] = s; psq[part][col] = sq;
    }
    __syncthreads();
    if (tid < 16) {
        float S = 0.f, SQ = 0.f;
        #pragma unroll
        for (int j = 0; j < 16; ++j) { S += psum[j][tid]; SQ += psq[j][tid]; }
        float mu = S / 256.0f;
        float var = SQ / 256.0f - mu * mu;
        mu_s[tid] = mu;
        rs_s[tid] = rsqrtf(var + 1e-5f);
    }
    __syncthreads();
    #pragma unroll
    for (int i = 0; i < 2; ++i) {
        int idx = tid + i * 256;
        int p = idx >> 5, c8 = (idx & 31) * 8;
        float mu = mu_s[p], rcp = rs_s[p];
        bf16x8 xt, xn;
        #pragma unroll
        for (int j = 0; j < 8; ++j) {
            float v = tile[(c8 + j) * 17 + p];
            float n = (v - mu) * rcp * gs[c8 + j] + bs[c8 + j];
            xt[j] = f2bf(v); xn[j] = f2bf(n);
        }
        size_t o = (size_t)(m0 + p) * CC + c8;
        *(bf16x8*)&Xt16[o] = xt;              // for epi (in flight past barrier)
        *(bf16x8*)&Xn16[o] = xn;              // for epi
        *(bf16x8*)&Xt_lds[p * 264 + c8] = xt; // for proj (LDS, on-chip)
        *(bf16x8*)&Xn_lds[p * 264 + c8] = xn;
    }
    // lgkm-only barrier: LDS tiles visible; fp32-tile reads retired (Vt
    // overlay safe). Global Xt16/Xn16 stores stay in flight.
    asm volatile("s_waitcnt lgkmcnt(0)" ::: "memory");
    __builtin_amdgcn_s_barrier();
    __builtin_amdgcn_sched_barrier(0);

    // ---------------- proj phase (wave-specialized, A-frags from LDS) ------
    if (w < 2) {
        // ---- w0: Q, w1: K — 16 rows x 96 cols, wave-local norm ----
        const bool isQ = (w == 0);
        const int woff = isQ ? OFF_WQ : OFF_WK;

        f32x4 acc[6];
        #pragma unroll
        for (int i = 0; i < 6; ++i) acc[i] = (f32x4){0.f, 0.f, 0.f, 0.f};

        #pragma unroll
        for (int kt = 0; kt < 8; ++kt) {
            bf16x8 af = *(const bf16x8*)&Xn_lds[ln * 264 + kt * 32 + quad * 8];
            #pragma unroll
            for (int nt = 0; nt < 6; ++nt) {
                bf16x8 bf = *(const bf16x8*)&W16[woff + (size_t)(nt * 16 + ln) * 256 + kt * 32 + quad * 8];
                acc[nt] = __builtin_amdgcn_mfma_f32_16x16x32_bf16(af, bf, acc[nt], 0, 0, 0);
            }
        }

        short* outp = isQ ? Q16 : K16;
        #pragma unroll
        for (int r = 0; r < 4; ++r) {
            int row = m0 + quad * 4 + r;
            float mrow = isQ ? mask[row] : 0.f;
            float vals[6];
            float ss = 0.f;
            #pragma unroll
            for (int nt = 0; nt < 6; ++nt) {
                float v = acc[nt][r];
                if (isQ) v += mrow * w_qm[nt * 16 + ln];
                vals[nt] = v;
                ss += v * v;
            }
            ss += __shfl_xor(ss, 1, 64); ss += __shfl_xor(ss, 2, 64);
            ss += __shfl_xor(ss, 4, 64); ss += __shfl_xor(ss, 8, 64);
            float sc = 1.0f / fmaxf(sqrtf(ss), 1e-12f);
            #pragma unroll
            for (int nt = 0; nt < 6; ++nt)
                outp[(size_t)row * EE + nt * 16 + ln] = f2bf(vals[nt] * sc);
        }
    } else {
        // ---- w2/w3: V projection, 16 rows x 128 cols each ----
        const int wn = w - 2;

        f32x4 acc[8];
        #pragma unroll
        for (int i = 0; i < 8; ++i) acc[i] = (f32x4){0.f, 0.f, 0.f, 0.f};

        #pragma unroll
        for (int kt = 0; kt < 8; ++kt) {
            bf16x8 af = *(const bf16x8*)&Xt_lds[ln * 264 + kt * 32 + quad * 8];
            #pragma unroll
            for (int nt = 0; nt < 8; ++nt) {
                int col = wn * 128 + nt * 16 + ln;
                bf16x8 bf = *(const bf16x8*)&W16[OFF_WV + (size_t)col * 256 + kt * 32 + quad * 8];
                acc[nt] = __builtin_amdgcn_mfma_f32_16x16x32_bf16(af, bf, acc[nt], 0, 0, 0);
            }
        }
        #pragma unroll
        for (int nt = 0; nt < 8; ++nt) {
            int ch = wn * 128 + nt * 16 + ln;
            #pragma unroll
            for (int r = 0; r < 4; ++r)
                Vt[ch * 24 + quad * 4 + r] = f2bf(acc[nt][r]);
        }
    }
    // lgkm-only barrier: Vt writes visible; Q/K global stores stay in flight.
    asm volatile("s_waitcnt lgkmcnt(0)" ::: "memory");
    __builtin_amdgcn_s_barrier();
    __builtin_amdgcn_sched_barrier(0);

    // ---- V16t store: 256 ch x 16 pos ----
    #pragma unroll
    for (int i = 0; i < 2; ++i) {
        int idx = tid + i * 256;
        int ch = idx >> 1, p8 = (idx & 1) * 8;
        *(bf16x8*)&V16t[((size_t)b * CC + ch) * NN + p0 + p8] =
            *(const bf16x8*)&Vt[ch * 24 + p8];
    }
}

// ---------------------------------------------------------------------------
// Kernel 2: MFMA attention, 4-way K-split. v10 = v9 (94.4us) + VALU cuts:
//  - softmax via exp2f with log2e folded into the constant (saves 1 v_mul
//    per exp; v_exp_f32 is natively 2^x).
//  - f2bf fast path (header change).
// Schedule bit-identical to v9 (single barrier, T14 issue-early K DMA).
// ---------------------------------------------------------------------------
__global__ __launch_bounds__(256, 4) void attn_kernel(
    const short* __restrict__ Q16, const short* __restrict__ K16,
    const short* __restrict__ V16t, const float* __restrict__ mask,
    short* __restrict__ Opart, float* __restrict__ Lpart)
{
    __shared__ short Ks[2][3072];     // [buf][p 0..11][key 0..31] chunks of 8 shorts
    __shared__ short Ps[2][2560];     // [buf][64 rows][40] (stride-40 padded)

    const int tid = threadIdx.x;
    const int w = tid >> 6, lane = tid & 63, ln = lane & 15, quad = lane >> 4;
    const int bidx = blockIdx.x;
    const int kg = bidx >> 8;                       // 0..3 key group
    const int qg = bidx & 255;
    const int b  = (qg & 7) >> 1;                   // XCD-pinned batch
    const int qt = ((qg >> 3) << 1) | (qg & 1);     // 0..63
    const int q0 = qt * 64;
    const size_t bN = (size_t)b * NN;
    const size_t bCC = (size_t)b * CC;
    const int kbase = kg * 1024;
    const float C2 = 1.47244446077890f;             // (10/sqrt(96))*log2(e)
    const int wbase = w * 64;

    #define STAGEK(buf, kk)                                                         \
        do {                                                                        \
            gld16(&Ks[buf][wbase * 8],                                              \
                  &K16[(bN + (kk) + (tid & 31)) * EE + (tid >> 5) * 8]);            \
            if (w < 2)                                                              \
                gld16(&Ks[buf][(256 + wbase) * 8],                                  \
                      &K16[(bN + (kk) + (tid & 31)) * EE + (8 + (tid >> 5)) * 8]);  \
        } while (0)

    bf16x8 qf[3];
    #pragma unroll
    for (int e = 0; e < 3; ++e)
        qf[e] = *(const bf16x8*)&Q16[(bN + q0 + w * 16 + ln) * EE + e * 32 + quad * 8];

    f32x4 acc[4][4];
    #pragma unroll
    for (int mt = 0; mt < 4; ++mt)
        #pragma unroll
        for (int nt = 0; nt < 4; ++nt) acc[mt][nt] = (f32x4){0.f, 0.f, 0.f, 0.f};
    float lsum[4] = {0.f, 0.f, 0.f, 0.f};

    // prologue: K(0)->Ks[0], K(1)->Ks[1]; full drain outside the loop.
    STAGEK(0, kbase);
    STAGEK(1, kbase + 32);
    __syncthreads();

    for (int it = 0; it < 32; ++it) {
        const int k0 = kbase + it * 32;
        const int cur = it & 1;

        // V fragments + mask direct global->reg (QK+softmax of cover).
        bf16x8 vf[4];
        #pragma unroll
        for (int nt = 0; nt < 4; ++nt)
            vf[nt] = *(const bf16x8*)&V16t[(bCC + wbase + nt * 16 + ln) * NN + k0 + quad * 8];
        const float mk0 = mask[bN + k0 + ln];
        const float mk1 = mask[bN + k0 + 16 + ln];

        // ---- S = Q K^T (K from LDS buffer cur; landed a full period ago) ----
        f32x4 s0 = (f32x4){0.f,0.f,0.f,0.f}, s1 = s0;
        __builtin_amdgcn_s_setprio(1);
        #pragma unroll
        for (int e = 0; e < 3; ++e) {
            bf16x8 kf0 = *(const bf16x8*)&Ks[cur][((e * 4 + quad) * 32 + ln) * 8];
            bf16x8 kf1 = *(const bf16x8*)&Ks[cur][((e * 4 + quad) * 32 + 16 + ln) * 8];
            s0 = __builtin_amdgcn_mfma_f32_16x16x32_bf16(qf[e], kf0, s0, 0, 0, 0);
            s1 = __builtin_amdgcn_mfma_f32_16x16x32_bf16(qf[e], kf1, s1, 0, 0, 0);
        }
        __builtin_amdgcn_s_setprio(0);
        const bool z0 = mk0 >= 0.5f;
        const bool z1 = mk1 >= 0.5f;
        #pragma unroll
        for (int r = 0; r < 4; ++r) {
            float p0 = z0 ? 0.f : exp2f(fmaf(s0[r], C2, -C2));
            float p1 = z1 ? 0.f : exp2f(fmaf(s1[r], C2, -C2));
            lsum[r] += p0 + p1;
            Ps[cur][(w * 16 + quad * 4 + r) * 40 + ln]      = f2bf(p0);
            Ps[cur][(w * 16 + quad * 4 + r) * 40 + 16 + ln] = f2bf(p1);
        }
        // ---- the ONE barrier: publishes Ps(cur); drains K(it+1) DMA (issued
        // post-barrier(it-1), ~full period of cover) and this iter's vf/mask.
        asm volatile("s_waitcnt vmcnt(0) lgkmcnt(0)" ::: "memory");
        __builtin_amdgcn_s_barrier();
        __builtin_amdgcn_sched_barrier(0);

        // ---- T14 issue-early: K(it+2) into Ks[cur] — buffer just freed.
        if (it + 2 < 32) STAGEK(cur, k0 + 64);

        // ---- PV: all 64 q x this wave's 64 channels; V from registers ----
        __builtin_amdgcn_s_setprio(1);
        #pragma unroll
        for (int mt = 0; mt < 4; ++mt) {
            bf16x8 pf = *(const bf16x8*)&Ps[cur][(mt * 16 + ln) * 40 + quad * 8];
            #pragma unroll
            for (int nt = 0; nt < 4; ++nt)
                acc[mt][nt] = __builtin_amdgcn_mfma_f32_16x16x32_bf16(pf, vf[nt], acc[mt][nt], 0, 0, 0);
        }
        __builtin_amdgcn_s_setprio(0);
        // no end-of-iter barrier: next iter writes the OTHER Ps buffer, and
        // Ks[cur^1] (next QK source) was drained at this iter's barrier.
    }
    #undef STAGEK

    // ---- epilogue: partial l and partial O ----
    #pragma unroll
    for (int r = 0; r < 4; ++r) {
        float l = lsum[r];
        l += __shfl_xor(l, 1, 64); l += __shfl_xor(l, 2, 64);
        l += __shfl_xor(l, 4, 64); l += __shfl_xor(l, 8, 64);
        if (ln == 0)
            Lpart[(size_t)kg * NTOT + bN + q0 + w * 16 + quad * 4 + r] = l;
    }
    #pragma unroll
    for (int mt = 0; mt < 4; ++mt)
        #pragma unroll
        for (int nt = 0; nt < 4; ++nt)
            #pragma unroll
            for (int r = 0; r < 4; ++r)
                Opart[((size_t)kg * NTOT + bN + q0 + mt * 16 + quad * 4 + r) * 256
                      + wbase + nt * 16 + ln] = f2bf(acc[mt][nt][r]);
}

// ---------------------------------------------------------------------------
// Kernel 3: mega-fused epilogue. v8 = v7 (3-region rotation, 6 barriers)
// + input-load hoisting: Opart/Xn16/mask (P1) and Xt16 (P2 subtrahend) are
// pure inputs -> issued at kernel start so the first barrier's mandatory
// vmcnt(0) drain overlaps them with the lsh load (removes the serial
// lsh->barrier->load chain). Peak VGPR ~116 < 128, 4 blocks/CU kept.
// ---------------------------------------------------------------------------
__global__ __launch_bounds__(256, 4) void epi_kernel(
    const short* __restrict__ Opart, const float* __restrict__ Lpart,
    const short* __restrict__ W16, const short* __restrict__ Xt16,
    const short* __restrict__ Xn16, const float* __restrict__ mask,
    const float* __restrict__ rs, const float* __restrict__ x,
    float* __restrict__ out)
{
    __shared__ char lds[37696];
    short* Olds  = (short*)lds;              // region A: 16 x 264 (P1-P2)
    short* Clds  = (short*)lds;              // region A reuse (P4-P5)
    short* Dlds  = (short*)(lds + 8448);     // region B: 16 x 528 (P1-P3)
    short* Hlds  = (short*)(lds + 25344);    // region C: 16 x 264 (P3-P4)
    short* tileB = (short*)(lds + 25344);    // region C reuse: 256 x 24 (P5+)
    float* lsh   = (float*)(lds + 37632);    // 16

    const int tid = threadIdx.x;
    const int w = tid >> 6, lane = tid & 63, ln = lane & 15, quad = lane >> 4;
    const int m0 = blockIdx.x * 16;
    const int b = m0 >> 12, p0l = m0 & 4095;

    // ---- hoisted input loads (pure inputs; overlap the barrier drain) ----
    bf16x8 ha0[2], ha1[2], ha2[2], ha3[2], hxn[2];
    float  hmq[2];
    #pragma unroll
    for (int i = 0; i < 2; ++i) {
        int idx = tid + i * 256;
        int q = idx >> 5, ch8 = (idx & 31) * 8;
        size_t base = (size_t)(m0 + q) * 256 + ch8;
        ha0[i] = *(const bf16x8*)&Opart[base];
        ha1[i] = *(const bf16x8*)&Opart[(size_t)NTOT * 256 + base];
        ha2[i] = *(const bf16x8*)&Opart[(size_t)2 * NTOT * 256 + base];
        ha3[i] = *(const bf16x8*)&Opart[(size_t)3 * NTOT * 256 + base];
        hxn[i] = *(const bf16x8*)&Xn16[base];
        hmq[i] = mask[m0 + q];
    }
    short xtv[4][4];
    #pragma unroll
    for (int nt = 0; nt < 4; ++nt)
        #pragma unroll
        for (int r = 0; r < 4; ++r)
            xtv[nt][r] = Xt16[(size_t)(m0 + quad * 4 + r) * 256 + (w * 64 + nt * 16 + ln)];

    if (tid < 16) {
        int g = m0 + tid;
        lsh[tid] = 1.0f / (Lpart[g] + Lpart[NTOT + g] + Lpart[2 * NTOT + g] + Lpart[3 * NTOT + g]);
    }
    __syncthreads();

    // ---- P1: combine partials (from hoisted regs) -> Olds; Xnm -> Dlds ----
    #pragma unroll
    for (int i = 0; i < 2; ++i) {
        int idx = tid + i * 256;
        int q = idx >> 5, ch8 = (idx & 31) * 8;
        float linv = lsh[q];
        bf16x8 o;
        #pragma unroll
        for (int e = 0; e < 8; ++e)
            o[e] = f2bf((bf2f(ha0[i][e]) + bf2f(ha1[i][e]) + bf2f(ha2[i][e]) + bf2f(ha3[i][e])) * linv);
        *(bf16x8*)&Olds[q * 264 + ch8] = o;
        bf16x8 xm;
        #pragma unroll
        for (int e = 0; e < 8; ++e) xm[e] = f2bf(bf2f(hxn[i][e]) * hmq[i]);
        *(bf16x8*)&Dlds[q * 528 + 256 + ch8] = xm;
    }
    __syncthreads();

    // ---- P2: D1 = O@wo^T - Xt (reads A, writes B-lower) ----
    {
        f32x4 acc[4];
        #pragma unroll
        for (int i = 0; i < 4; ++i) acc[i] = (f32x4){0.f, 0.f, 0.f, 0.f};
        #pragma unroll
        for (int kt = 0; kt < 8; ++kt) {
            bf16x8 af = *(const bf16x8*)&Olds[ln * 264 + kt * 32 + quad * 8];
            #pragma unroll
            for (int nt = 0; nt < 4; ++nt) {
                int col = w * 64 + nt * 16 + ln;
                bf16x8 bf = *(const bf16x8*)&W16[OFF_WO + (size_t)col * 256 + kt * 32 + quad * 8];
                acc[nt] = __builtin_amdgcn_mfma_f32_16x16x32_bf16(af, bf, acc[nt], 0, 0, 0);
            }
        }
        #pragma unroll
        for (int nt = 0; nt < 4; ++nt) {
            int col = w * 64 + nt * 16 + ln;
            #pragma unroll
            for (int r = 0; r < 4; ++r) {
                int row = quad * 4 + r;
                float v = acc[nt][r] - bf2f(xtv[nt][r]);
                Dlds[row * 528 + col] = f2bf(v);
            }
        }
    }
    __syncthreads();

    // ---- P3: Hid = gelu([D1|Xnm] @ wd1^T) (reads B, writes C) ----
    {
        f32x4 acc[4];
        #pragma unroll
        for (int i = 0; i < 4; ++i) acc[i] = (f32x4){0.f, 0.f, 0.f, 0.f};
        #pragma unroll
        for (int kt = 0; kt < 16; ++kt) {
            bf16x8 af = *(const bf16x8*)&Dlds[ln * 528 + kt * 32 + quad * 8];
            #pragma unroll
            for (int nt = 0; nt < 4; ++nt) {
                int col = w * 64 + nt * 16 + ln;
                bf16x8 bf = *(const bf16x8*)&W16[OFF_WD1 + (size_t)col * 512 + kt * 32 + quad * 8];
                acc[nt] = __builtin_amdgcn_mfma_f32_16x16x32_bf16(af, bf, acc[nt], 0, 0, 0);
            }
        }
        #pragma unroll
        for (int nt = 0; nt < 4; ++nt) {
            int col = w * 64 + nt * 16 + ln;
            #pragma unroll
            for (int r = 0; r < 4; ++r) {
                int row = quad * 4 + r;
                Hlds[row * 264 + col] = f2bf(gelu_exact(acc[nt][r]));
            }
        }
    }
    __syncthreads();

    // ---- P4: Cor = Hid @ wd2^T (reads C, writes A; A last read in P2) ----
    {
        f32x4 acc[4];
        #pragma unroll
        for (int i = 0; i < 4; ++i) acc[i] = (f32x4){0.f, 0.f, 0.f, 0.f};
        #pragma unroll
        for (int kt = 0; kt < 8; ++kt) {
            bf16x8 af = *(const bf16x8*)&Hlds[ln * 264 + kt * 32 + quad * 8];
            #pragma unroll
            for (int nt = 0; nt < 4; ++nt) {
                int col = w * 64 + nt * 16 + ln;
                bf16x8 bf = *(const bf16x8*)&W16[OFF_WD2 + (size_t)col * 256 + kt * 32 + quad * 8];
                acc[nt] = __builtin_amdgcn_mfma_f32_16x16x32_bf16(af, bf, acc[nt], 0, 0, 0);
            }
        }
        #pragma unroll
        for (int nt = 0; nt < 4; ++nt) {
            int col = w * 64 + nt * 16 + ln;
            #pragma unroll
            for (int r = 0; r < 4; ++r) {
                int row = quad * 4 + r;
                Clds[row * 264 + col] = f2bf(acc[nt][r]);
            }
        }
    }
    __syncthreads();

    // ---- P5: gate GEMM + delta (reads A, writes C; C last read in P4) ----
    {
        f32x4 acc[4];
        #pragma unroll
        for (int i = 0; i < 4; ++i) acc[i] = (f32x4){0.f, 0.f, 0.f, 0.f};
        #pragma unroll
        for (int kt = 0; kt < 8; ++kt) {
            bf16x8 af = *(const bf16x8*)&Clds[ln * 264 + kt * 32 + quad * 8];
            #pragma unroll
            for (int nt = 0; nt < 4; ++nt) {
                int col = w * 64 + nt * 16 + ln;
                bf16x8 bf = *(const bf16x8*)&W16[OFF_WG + (size_t)col * 256 + kt * 32 + quad * 8];
                acc[nt] = __builtin_amdgcn_mfma_f32_16x16x32_bf16(af, bf, acc[nt], 0, 0, 0);
            }
        }
        float trs = tanhf(rs[0]);
        #pragma unroll
        for (int nt = 0; nt < 4; ++nt) {
            int col = w * 64 + nt * 16 + ln;
            float wgl = bf2f(W16[OFF_WGL + col]);
            #pragma unroll
            for (int r = 0; r < 4; ++r) {
                int row = quad * 4 + r;
                float mrow = mask[m0 + row];
                float logit = acc[nt][r] + mrow * wgl;
                float gate = mrow / (1.0f + __expf(-logit));
                float corr = bf2f(Clds[row * 264 + col]);
                tileB[col * 24 + row] = f2bf(trs * gate * corr);
            }
        }
    }
    __syncthreads();

    // ---- store: out[b,ch,p] = x + delta (256 ch x 16 pos) ----
    #pragma unroll
    for (int i = 0; i < 2; ++i) {
        int idx = tid + i * 256;
        int ch = idx >> 1, p8 = (idx & 1) * 8;
        bf16x8 d = *(const bf16x8*)&tileB[ch * 24 + p8];
        size_t o = ((size_t)b * CC + ch) * NN + p0l + p8;
        float4 x0 = *(const float4*)&x[o];
        float4 x1 = *(const float4*)&x[o + 4];
        float4 o0, o1;
        o0.x = x0.x + bf2f(d[0]); o0.y = x0.y + bf2f(d[1]);
        o0.z = x0.z + bf2f(d[2]); o0.w = x0.w + bf2f(d[3]);
        o1.x = x1.x + bf2f(d[4]); o1.y = x1.y + bf2f(d[5]);
        o1.z = x1.z + bf2f(d[6]); o1.w = x1.w + bf2f(d[7]);
        *(float4*)&out[o] = o0;
        *(float4*)&out[o + 4] = o1;
    }
}

// ---------------------------------------------------------------------------
extern "C" void kernel_launch(void* const* d_in, const int* in_sizes, int n_in,
                              void* d_out, int out_size, void* d_ws, size_t ws_size,
                              hipStream_t stream) {
    const float* x     = (const float*)d_in[0];
    const float* mask  = (const float*)d_in[1];
    const float* gamma = (const float*)d_in[2];
    const float* beta  = (const float*)d_in[3];
    const float* wq    = (const float*)d_in[4];
    const float* wk    = (const float*)d_in[5];
    const float* wv    = (const float*)d_in[6];
    const float* w_out = (const float*)d_in[7];
    const float* w_qm  = (const float*)d_in[8];
    const float* wd1   = (const float*)d_in[9];
    const float* wd2   = (const float*)d_in[10];
    const float* wg    = (const float*)d_in[11];
    const float* rs    = (const float*)d_in[12];
    float* out = (float*)d_out;

    const size_t NC = (size_t)NTOT * CC;
    const size_t NE = (size_t)NTOT * EE;
    short* Xn16  = (short*)d_ws;        // NC
    short* Xt16  = Xn16 + NC;           // NC
    short* Q16   = Xt16 + NC;           // NE
    short* K16   = Q16 + NE;            // NE
    short* V16t  = K16 + NE;            // NC
    short* W16   = V16t + NC;           // W16_TOTAL
    short* Opart = W16 + W16_TOTAL;     // 4*NC
    float* Lpart = (float*)(Opart + 4 * NC);   // 4*NTOT f32
    // ~66 MB total

    wconv_kernel<<<(W16_TOTAL / 4 + 255) / 256, 256, 0, stream>>>(wq, wk, wv, w_out,
                                                                  wd1, wd2, wg, W16);
    lnproj_kernel<<<1024, 256, 0, stream>>>(x, gamma, beta, W16, mask, w_qm,
                                            Xt16, Xn16, Q16, K16, V16t);
    attn_kernel<<<1024, 256, 0, stream>>>(Q16, K16, V16t, mask, Opart, Lpart);
    epi_kernel<<<1024, 256, 0, stream>>>(Opart, Lpart, W16, Xt16, Xn16, mask,
                                         rs, x, out);
}

// Round 12
// 291.216 us; speedup vs baseline: 1.0091x; 1.0091x over previous
//
#include <hip/hip_runtime.h>
#include <hip/hip_bf16.h>
#include <math.h>

// Problem constants
#define BB 4
#define CC 256
#define NN 4096          // H*W
#define EE 96
#define NTOT (BB*NN)     // 16384 rows

typedef __attribute__((ext_vector_type(8))) short bf16x8;
typedef __attribute__((ext_vector_type(4))) float f32x4;

// NATIVE fp32->bf16 (gfx950 has a HW convert; the compiler also pairs
// adjacent converts into v_cvt_pk_bf16_f32). Round-11 lesson: the integer
// RNE bit-trick was 3-4 VALU ops vs 1 and raised VALUBusy 24->33%.
__device__ __forceinline__ short f2bf(float x) {
    __hip_bfloat16 h = __float2bfloat16(x);
    return *reinterpret_cast<short*>(&h);
}
__device__ __forceinline__ float bf2f(short s) {
    unsigned int u = ((unsigned int)(unsigned short)s) << 16;
    float f;
    __builtin_memcpy(&f, &u, 4);
    return f;
}
__device__ __forceinline__ float gelu_exact(float v) {
    return 0.5f * v * (1.0f + erff(v * 0.70710678118654752f));
}
// async global->LDS, 16B per lane; LDS dest = uniform base + lane*16
__device__ __forceinline__ void gld16(void* lds, const void* g) {
    __builtin_amdgcn_global_load_lds(
        (const __attribute__((address_space(1))) unsigned int*)g,
        (__attribute__((address_space(3))) unsigned int*)lds, 16, 0, 0);
}

// Weight arena offsets (shorts). wg split into 256-stride matrix + last col.
#define OFF_WQ  0
#define OFF_WK  24576
#define OFF_WV  49152
#define OFF_WO  114688
#define OFF_WD1 180224
#define OFF_WD2 311296
#define OFF_WG  376832
#define OFF_WGL 442368
#define W16_TOTAL 442624

// ---------------------------------------------------------------------------
// Kernel 0: weight fp32 -> bf16 converter. 4 elements/thread + short4 store.
// ---------------------------------------------------------------------------
__global__ void wconv_kernel(const float* __restrict__ wq, const float* __restrict__ wk,
                             const float* __restrict__ wv, const float* __restrict__ wo,
                             const float* __restrict__ wd1, const float* __restrict__ wd2,
                             const float* __restrict__ wg, short* __restrict__ W16) {
    int i0 = (blockIdx.x * 256 + threadIdx.x) * 4;
    if (i0 >= W16_TOTAL) return;
    short4 o;
    #pragma unroll
    for (int j = 0; j < 4; ++j) {
        int i = i0 + j;
        float v;
        if      (i < OFF_WK)  v = wq[i];
        else if (i < OFF_WV)  v = wk[i - OFF_WK];
        else if (i < OFF_WO)  v = wv[i - OFF_WV];
        else if (i < OFF_WD1) v = wo[i - OFF_WO];
        else if (i < OFF_WD2) v = wd1[i - OFF_WD1];
        else if (i < OFF_WG)  v = wd2[i - OFF_WD2];
        else if (i < OFF_WGL) { int l = i - OFF_WG; v = wg[(l >> 8) * 257 + (l & 255)]; }
        else                  v = wg[(i - OFF_WGL) * 257 + 256];
        ((short*)&o)[j] = f2bf(v);
    }
    *(short4*)&W16[i0] = o;
}

// ---------------------------------------------------------------------------
// Kernel 1: fused LayerNorm + Q/K/V projections. v3 kept (16 rows/block,
// grid 1024, 4 blocks/CU, wave-specialized proj, LDS-resident A-frags,
// lgkm-only mid barriers).
// ---------------------------------------------------------------------------
__global__ __launch_bounds__(256) void lnproj_kernel(
    const float* __restrict__ x, const float* __restrict__ gamma,
    const float* __restrict__ beta, const short* __restrict__ W16,
    const float* __restrict__ mask, const float* __restrict__ w_qm,
    short* __restrict__ Xt16, short* __restrict__ Xn16,
    short* __restrict__ Q16, short* __restrict__ K16,
    short* __restrict__ V16t)
{
    __shared__ char ldsbuf[17408];            // fp32 tile 256x17 | later Vt 256x24 b16
    float* tile = (float*)ldsbuf;
    short* Vt   = (short*)ldsbuf;
    __shared__ short Xn_lds[16 * 264];        // proj A-frags (normed)
    __shared__ short Xt_lds[16 * 264];        // proj A-frags (raw x)
    __shared__ float psum[16][16], psq[16][16];
    __shared__ float mu_s[16], rs_s[16];
    __shared__ float gs[256], bs[256];

    const int tid = threadIdx.x;
    const int w = tid >> 6, lane = tid & 63, ln = lane & 15, quad = lane >> 4;
    const int b  = blockIdx.x >> 8;
    const int p0 = (blockIdx.x & 255) * 16;
    const int m0 = blockIdx.x * 16;           // global row base (= b*NN + p0)
    const float* xb = x + (size_t)b * CC * NN;

    // ---------------- ln phase ----------------
    gs[tid] = gamma[tid];
    bs[tid] = beta[tid];
    #pragma unroll
    for (int i = 0; i < 4; ++i) {
        int idx = tid + i * 256;
        int c = idx >> 2, p4 = (idx & 3) * 4;
        float4 v = *(const float4*)&xb[(size_t)c * NN + p0 + p4];
        tile[c * 17 + p4]     = v.x;
        tile[c * 17 + p4 + 1] = v.y;
        tile[c * 17 + p4 + 2] = v.z;
        tile[c * 17 + p4 + 3] = v.w;
    }
    __syncthreads();
    {
        int col = tid & 15, part = tid >> 4;   // 16 parts x 16 positions
        float s = 0.f, sq = 0.f;
        for (int r = part * 16; r < part * 16 + 16; ++r) {
            float v = tile[r * 17 + col];
            s += v; sq += v * v;
        }
        psum[part][col] = s; psq[part][col] = sq;
    }
    __syncthreads();
    if (tid < 16) {
        float S = 0.f, SQ = 0.f;
        #pragma unroll
        for (int j = 0; j < 16; ++j) { S += psum[j][tid]; SQ += psq[j][tid]; }
        float mu = S / 256.0f;
        float var = SQ / 256.0f - mu * mu;
        mu_s[tid] = mu;
        rs_s[tid] = rsqrtf(var + 1e-5f);
    }
    __syncthreads();
    #pragma unroll
    for (int i = 0; i < 2; ++i) {
        int idx = tid + i * 256;
        int p = idx >> 5, c8 = (idx & 31) * 8;
        float mu = mu_s[p], rcp = rs_s[p];
        bf16x8 xt, xn;
        #pragma unroll
        for (int j = 0; j < 8; ++j) {
            float v = tile[(c8 + j) * 17 + p];
            float n = (v - mu) * rcp * gs[c8 + j] + bs[c8 + j];
            xt[j] = f2bf(v); xn[j] = f2bf(n);
        }
        size_t o = (size_t)(m0 + p) * CC + c8;
        *(bf16x8*)&Xt16[o] = xt;              // for epi (in flight past barrier)
        *(bf16x8*)&Xn16[o] = xn;              // for epi
        *(bf16x8*)&Xt_lds[p * 264 + c8] = xt; // for proj (LDS, on-chip)
        *(bf16x8*)&Xn_lds[p * 264 + c8] = xn;
    }
    // lgkm-only barrier: LDS tiles visible; fp32-tile reads retired (Vt
    // overlay safe). Global Xt16/Xn16 stores stay in flight.
    asm volatile("s_waitcnt lgkmcnt(0)" ::: "memory");
    __builtin_amdgcn_s_barrier();
    __builtin_amdgcn_sched_barrier(0);

    // ---------------- proj phase (wave-specialized, A-frags from LDS) ------
    if (w < 2) {
        // ---- w0: Q, w1: K — 16 rows x 96 cols, wave-local norm ----
        const bool isQ = (w == 0);
        const int woff = isQ ? OFF_WQ : OFF_WK;

        f32x4 acc[6];
        #pragma unroll
        for (int i = 0; i < 6; ++i) acc[i] = (f32x4){0.f, 0.f, 0.f, 0.f};

        #pragma unroll
        for (int kt = 0; kt < 8; ++kt) {
            bf16x8 af = *(const bf16x8*)&Xn_lds[ln * 264 + kt * 32 + quad * 8];
            #pragma unroll
            for (int nt = 0; nt < 6; ++nt) {
                bf16x8 bf = *(const bf16x8*)&W16[woff + (size_t)(nt * 16 + ln) * 256 + kt * 32 + quad * 8];
                acc[nt] = __builtin_amdgcn_mfma_f32_16x16x32_bf16(af, bf, acc[nt], 0, 0, 0);
            }
        }

        short* outp = isQ ? Q16 : K16;
        #pragma unroll
        for (int r = 0; r < 4; ++r) {
            int row = m0 + quad * 4 + r;
            float mrow = isQ ? mask[row] : 0.f;
            float vals[6];
            float ss = 0.f;
            #pragma unroll
            for (int nt = 0; nt < 6; ++nt) {
                float v = acc[nt][r];
                if (isQ) v += mrow * w_qm[nt * 16 + ln];
                vals[nt] = v;
                ss += v * v;
            }
            ss += __shfl_xor(ss, 1, 64); ss += __shfl_xor(ss, 2, 64);
            ss += __shfl_xor(ss, 4, 64); ss += __shfl_xor(ss, 8, 64);
            float sc = 1.0f / fmaxf(sqrtf(ss), 1e-12f);
            #pragma unroll
            for (int nt = 0; nt < 6; ++nt)
                outp[(size_t)row * EE + nt * 16 + ln] = f2bf(vals[nt] * sc);
        }
    } else {
        // ---- w2/w3: V projection, 16 rows x 128 cols each ----
        const int wn = w - 2;

        f32x4 acc[8];
        #pragma unroll
        for (int i = 0; i < 8; ++i) acc[i] = (f32x4){0.f, 0.f, 0.f, 0.f};

        #pragma unroll
        for (int kt = 0; kt < 8; ++kt) {
            bf16x8 af = *(const bf16x8*)&Xt_lds[ln * 264 + kt * 32 + quad * 8];
            #pragma unroll
            for (int nt = 0; nt < 8; ++nt) {
                int col = wn * 128 + nt * 16 + ln;
                bf16x8 bf = *(const bf16x8*)&W16[OFF_WV + (size_t)col * 256 + kt * 32 + quad * 8];
                acc[nt] = __builtin_amdgcn_mfma_f32_16x16x32_bf16(af, bf, acc[nt], 0, 0, 0);
            }
        }
        #pragma unroll
        for (int nt = 0; nt < 8; ++nt) {
            int ch = wn * 128 + nt * 16 + ln;
            #pragma unroll
            for (int r = 0; r < 4; ++r)
                Vt[ch * 24 + quad * 4 + r] = f2bf(acc[nt][r]);
        }
    }
    // lgkm-only barrier: Vt writes visible; Q/K global stores stay in flight.
    asm volatile("s_waitcnt lgkmcnt(0)" ::: "memory");
    __builtin_amdgcn_s_barrier();
    __builtin_amdgcn_sched_barrier(0);

    // ---- V16t store: 256 ch x 16 pos ----
    #pragma unroll
    for (int i = 0; i < 2; ++i) {
        int idx = tid + i * 256;
        int ch = idx >> 1, p8 = (idx & 1) * 8;
        *(bf16x8*)&V16t[((size_t)b * CC + ch) * NN + p0 + p8] =
            *(const bf16x8*)&Vt[ch * 24 + p8];
    }
}

// ---------------------------------------------------------------------------
// Kernel 2: MFMA attention, 4-way K-split. v10 schedule kept (v9 94.4us):
// single barrier/iter, T14 issue-early K DMA, exp2f softmax with folded
// log2e constant. f2bf reverted to native convert (round-11 lesson).
// ---------------------------------------------------------------------------
__global__ __launch_bounds__(256, 4) void attn_kernel(
    const short* __restrict__ Q16, const short* __restrict__ K16,
    const short* __restrict__ V16t, const float* __restrict__ mask,
    short* __restrict__ Opart, float* __restrict__ Lpart)
{
    __shared__ short Ks[2][3072];     // [buf][p 0..11][key 0..31] chunks of 8 shorts
    __shared__ short Ps[2][2560];     // [buf][64 rows][40] (stride-40 padded)

    const int tid = threadIdx.x;
    const int w = tid >> 6, lane = tid & 63, ln = lane & 15, quad = lane >> 4;
    const int bidx = blockIdx.x;
    const int kg = bidx >> 8;                       // 0..3 key group
    const int qg = bidx & 255;
    const int b  = (qg & 7) >> 1;                   // XCD-pinned batch
    const int qt = ((qg >> 3) << 1) | (qg & 1);     // 0..63
    const int q0 = qt * 64;
    const size_t bN = (size_t)b * NN;
    const size_t bCC = (size_t)b * CC;
    const int kbase = kg * 1024;
    const float C2 = 1.47244446077890f;             // (10/sqrt(96))*log2(e)
    const int wbase = w * 64;

    #define STAGEK(buf, kk)                                                         \
        do {                                                                        \
            gld16(&Ks[buf][wbase * 8],                                              \
                  &K16[(bN + (kk) + (tid & 31)) * EE + (tid >> 5) * 8]);            \
            if (w < 2)                                                              \
                gld16(&Ks[buf][(256 + wbase) * 8],                                  \
                      &K16[(bN + (kk) + (tid & 31)) * EE + (8 + (tid >> 5)) * 8]);  \
        } while (0)

    bf16x8 qf[3];
    #pragma unroll
    for (int e = 0; e < 3; ++e)
        qf[e] = *(const bf16x8*)&Q16[(bN + q0 + w * 16 + ln) * EE + e * 32 + quad * 8];

    f32x4 acc[4][4];
    #pragma unroll
    for (int mt = 0; mt < 4; ++mt)
        #pragma unroll
        for (int nt = 0; nt < 4; ++nt) acc[mt][nt] = (f32x4){0.f, 0.f, 0.f, 0.f};
    float lsum[4] = {0.f, 0.f, 0.f, 0.f};

    // prologue: K(0)->Ks[0], K(1)->Ks[1]; full drain outside the loop.
    STAGEK(0, kbase);
    STAGEK(1, kbase + 32);
    __syncthreads();

    for (int it = 0; it < 32; ++it) {
        const int k0 = kbase + it * 32;
        const int cur = it & 1;

        // V fragments + mask direct global->reg (QK+softmax of cover).
        bf16x8 vf[4];
        #pragma unroll
        for (int nt = 0; nt < 4; ++nt)
            vf[nt] = *(const bf16x8*)&V16t[(bCC + wbase + nt * 16 + ln) * NN + k0 + quad * 8];
        const float mk0 = mask[bN + k0 + ln];
        const float mk1 = mask[bN + k0 + 16 + ln];

        // ---- S = Q K^T (K from LDS buffer cur; landed a full period ago) ----
        f32x4 s0 = (f32x4){0.f,0.f,0.f,0.f}, s1 = s0;
        __builtin_amdgcn_s_setprio(1);
        #pragma unroll
        for (int e = 0; e < 3; ++e) {
            bf16x8 kf0 = *(const bf16x8*)&Ks[cur][((e * 4 + quad) * 32 + ln) * 8];
            bf16x8 kf1 = *(const bf16x8*)&Ks[cur][((e * 4 + quad) * 32 + 16 + ln) * 8];
            s0 = __builtin_amdgcn_mfma_f32_16x16x32_bf16(qf[e], kf0, s0, 0, 0, 0);
            s1 = __builtin_amdgcn_mfma_f32_16x16x32_bf16(qf[e], kf1, s1, 0, 0, 0);
        }
        __builtin_amdgcn_s_setprio(0);
        const bool z0 = mk0 >= 0.5f;
        const bool z1 = mk1 >= 0.5f;
        #pragma unroll
        for (int r = 0; r < 4; ++r) {
            float p0 = z0 ? 0.f : exp2f(fmaf(s0[r], C2, -C2));
            float p1 = z1 ? 0.f : exp2f(fmaf(s1[r], C2, -C2));
            lsum[r] += p0 + p1;
            Ps[cur][(w * 16 + quad * 4 + r) * 40 + ln]      = f2bf(p0);
            Ps[cur][(w * 16 + quad * 4 + r) * 40 + 16 + ln] = f2bf(p1);
        }
        // ---- the ONE barrier: publishes Ps(cur); drains K(it+1) DMA (issued
        // post-barrier(it-1), ~full period of cover) and this iter's vf/mask.
        asm volatile("s_waitcnt vmcnt(0) lgkmcnt(0)" ::: "memory");
        __builtin_amdgcn_s_barrier();
        __builtin_amdgcn_sched_barrier(0);

        // ---- T14 issue-early: K(it+2) into Ks[cur] — buffer just freed.
        if (it + 2 < 32) STAGEK(cur, k0 + 64);

        // ---- PV: all 64 q x this wave's 64 channels; V from registers ----
        __builtin_amdgcn_s_setprio(1);
        #pragma unroll
        for (int mt = 0; mt < 4; ++mt) {
            bf16x8 pf = *(const bf16x8*)&Ps[cur][(mt * 16 + ln) * 40 + quad * 8];
            #pragma unroll
            for (int nt = 0; nt < 4; ++nt)
                acc[mt][nt] = __builtin_amdgcn_mfma_f32_16x16x32_bf16(pf, vf[nt], acc[mt][nt], 0, 0, 0);
        }
        __builtin_amdgcn_s_setprio(0);
        // no end-of-iter barrier: next iter writes the OTHER Ps buffer, and
        // Ks[cur^1] (next QK source) was drained at this iter's barrier.
    }
    #undef STAGEK

    // ---- epilogue: partial l and partial O ----
    #pragma unroll
    for (int r = 0; r < 4; ++r) {
        float l = lsum[r];
        l += __shfl_xor(l, 1, 64); l += __shfl_xor(l, 2, 64);
        l += __shfl_xor(l, 4, 64); l += __shfl_xor(l, 8, 64);
        if (ln == 0)
            Lpart[(size_t)kg * NTOT + bN + q0 + w * 16 + quad * 4 + r] = l;
    }
    #pragma unroll
    for (int mt = 0; mt < 4; ++mt)
        #pragma unroll
        for (int nt = 0; nt < 4; ++nt)
            #pragma unroll
            for (int r = 0; r < 4; ++r)
                Opart[((size_t)kg * NTOT + bN + q0 + mt * 16 + quad * 4 + r) * 256
                      + wbase + nt * 16 + ln] = f2bf(acc[mt][nt][r]);
}

// ---------------------------------------------------------------------------
// Kernel 3: mega-fused epilogue. v8 kept (3-region rotation, 6 barriers,
// hoisted input loads). f2bf reverted to native convert.
// ---------------------------------------------------------------------------
__global__ __launch_bounds__(256, 4) void epi_kernel(
    const short* __restrict__ Opart, const float* __restrict__ Lpart,
    const short* __restrict__ W16, const short* __restrict__ Xt16,
    const short* __restrict__ Xn16, const float* __restrict__ mask,
    const float* __restrict__ rs, const float* __restrict__ x,
    float* __restrict__ out)
{
    __shared__ char lds[37696];
    short* Olds  = (short*)lds;              // region A: 16 x 264 (P1-P2)
    short* Clds  = (short*)lds;              // region A reuse (P4-P5)
    short* Dlds  = (short*)(lds + 8448);     // region B: 16 x 528 (P1-P3)
    short* Hlds  = (short*)(lds + 25344);    // region C: 16 x 264 (P3-P4)
    short* tileB = (short*)(lds + 25344);    // region C reuse: 256 x 24 (P5+)
    float* lsh   = (float*)(lds + 37632);    // 16

    const int tid = threadIdx.x;
    const int w = tid >> 6, lane = tid & 63, ln = lane & 15, quad = lane >> 4;
    const int m0 = blockIdx.x * 16;
    const int b = m0 >> 12, p0l = m0 & 4095;

    // ---- hoisted input loads (pure inputs; overlap the barrier drain) ----
    bf16x8 ha0[2], ha1[2], ha2[2], ha3[2], hxn[2];
    float  hmq[2];
    #pragma unroll
    for (int i = 0; i < 2; ++i) {
        int idx = tid + i * 256;
        int q = idx >> 5, ch8 = (idx & 31) * 8;
        size_t base = (size_t)(m0 + q) * 256 + ch8;
        ha0[i] = *(const bf16x8*)&Opart[base];
        ha1[i] = *(const bf16x8*)&Opart[(size_t)NTOT * 256 + base];
        ha2[i] = *(const bf16x8*)&Opart[(size_t)2 * NTOT * 256 + base];
        ha3[i] = *(const bf16x8*)&Opart[(size_t)3 * NTOT * 256 + base];
        hxn[i] = *(const bf16x8*)&Xn16[base];
        hmq[i] = mask[m0 + q];
    }
    short xtv[4][4];
    #pragma unroll
    for (int nt = 0; nt < 4; ++nt)
        #pragma unroll
        for (int r = 0; r < 4; ++r)
            xtv[nt][r] = Xt16[(size_t)(m0 + quad * 4 + r) * 256 + (w * 64 + nt * 16 + ln)];

    if (tid < 16) {
        int g = m0 + tid;
        lsh[tid] = 1.0f / (Lpart[g] + Lpart[NTOT + g] + Lpart[2 * NTOT + g] + Lpart[3 * NTOT + g]);
    }
    __syncthreads();

    // ---- P1: combine partials (from hoisted regs) -> Olds; Xnm -> Dlds ----
    #pragma unroll
    for (int i = 0; i < 2; ++i) {
        int idx = tid + i * 256;
        int q = idx >> 5, ch8 = (idx & 31) * 8;
        float linv = lsh[q];
        bf16x8 o;
        #pragma unroll
        for (int e = 0; e < 8; ++e)
            o[e] = f2bf((bf2f(ha0[i][e]) + bf2f(ha1[i][e]) + bf2f(ha2[i][e]) + bf2f(ha3[i][e])) * linv);
        *(bf16x8*)&Olds[q * 264 + ch8] = o;
        bf16x8 xm;
        #pragma unroll
        for (int e = 0; e < 8; ++e) xm[e] = f2bf(bf2f(hxn[i][e]) * hmq[i]);
        *(bf16x8*)&Dlds[q * 528 + 256 + ch8] = xm;
    }
    __syncthreads();

    // ---- P2: D1 = O@wo^T - Xt (reads A, writes B-lower) ----
    {
        f32x4 acc[4];
        #pragma unroll
        for (int i = 0; i < 4; ++i) acc[i] = (f32x4){0.f, 0.f, 0.f, 0.f};
        #pragma unroll
        for (int kt = 0; kt < 8; ++kt) {
            bf16x8 af = *(const bf16x8*)&Olds[ln * 264 + kt * 32 + quad * 8];
            #pragma unroll
            for (int nt = 0; nt < 4; ++nt) {
                int col = w * 64 + nt * 16 + ln;
                bf16x8 bf = *(const bf16x8*)&W16[OFF_WO + (size_t)col * 256 + kt * 32 + quad * 8];
                acc[nt] = __builtin_amdgcn_mfma_f32_16x16x32_bf16(af, bf, acc[nt], 0, 0, 0);
            }
        }
        #pragma unroll
        for (int nt = 0; nt < 4; ++nt) {
            int col = w * 64 + nt * 16 + ln;
            #pragma unroll
            for (int r = 0; r < 4; ++r) {
                int row = quad * 4 + r;
                float v = acc[nt][r] - bf2f(xtv[nt][r]);
                Dlds[row * 528 + col] = f2bf(v);
            }
        }
    }
    __syncthreads();

    // ---- P3: Hid = gelu([D1|Xnm] @ wd1^T) (reads B, writes C) ----
    {
        f32x4 acc[4];
        #pragma unroll
        for (int i = 0; i < 4; ++i) acc[i] = (f32x4){0.f, 0.f, 0.f, 0.f};
        #pragma unroll
        for (int kt = 0; kt < 16; ++kt) {
            bf16x8 af = *(const bf16x8*)&Dlds[ln * 528 + kt * 32 + quad * 8];
            #pragma unroll
            for (int nt = 0; nt < 4; ++nt) {
                int col = w * 64 + nt * 16 + ln;
                bf16x8 bf = *(const bf16x8*)&W16[OFF_WD1 + (size_t)col * 512 + kt * 32 + quad * 8];
                acc[nt] = __builtin_amdgcn_mfma_f32_16x16x32_bf16(af, bf, acc[nt], 0, 0, 0);
            }
        }
        #pragma unroll
        for (int nt = 0; nt < 4; ++nt) {
            int col = w * 64 + nt * 16 + ln;
            #pragma unroll
            for (int r = 0; r < 4; ++r) {
                int row = quad * 4 + r;
                Hlds[row * 264 + col] = f2bf(gelu_exact(acc[nt][r]));
            }
        }
    }
    __syncthreads();

    // ---- P4: Cor = Hid @ wd2^T (reads C, writes A; A last read in P2) ----
    {
        f32x4 acc[4];
        #pragma unroll
        for (int i = 0; i < 4; ++i) acc[i] = (f32x4){0.f, 0.f, 0.f, 0.f};
        #pragma unroll
        for (int kt = 0; kt < 8; ++kt) {
            bf16x8 af = *(const bf16x8*)&Hlds[ln * 264 + kt * 32 + quad * 8];
            #pragma unroll
            for (int nt = 0; nt < 4; ++nt) {
                int col = w * 64 + nt * 16 + ln;
                bf16x8 bf = *(const bf16x8*)&W16[OFF_WD2 + (size_t)col * 256 + kt * 32 + quad * 8];
                acc[nt] = __builtin_amdgcn_mfma_f32_16x16x32_bf16(af, bf, acc[nt], 0, 0, 0);
            }
        }
        #pragma unroll
        for (int nt = 0; nt < 4; ++nt) {
            int col = w * 64 + nt * 16 + ln;
            #pragma unroll
            for (int r = 0; r < 4; ++r) {
                int row = quad * 4 + r;
                Clds[row * 264 + col] = f2bf(acc[nt][r]);
            }
        }
    }
    __syncthreads();

    // ---- P5: gate GEMM + delta (reads A, writes C; C last read in P4) ----
    {
        f32x4 acc[4];
        #pragma unroll
        for (int i = 0; i < 4; ++i) acc[i] = (f32x4){0.f, 0.f, 0.f, 0.f};
        #pragma unroll
        for (int kt = 0; kt < 8; ++kt) {
            bf16x8 af = *(const bf16x8*)&Clds[ln * 264 + kt * 32 + quad * 8];
            #pragma unroll
            for (int nt = 0; nt < 4; ++nt) {
                int col = w * 64 + nt * 16 + ln;
                bf16x8 bf = *(const bf16x8*)&W16[OFF_WG + (size_t)col * 256 + kt * 32 + quad * 8];
                acc[nt] = __builtin_amdgcn_mfma_f32_16x16x32_bf16(af, bf, acc[nt], 0, 0, 0);
            }
        }
        float trs = tanhf(rs[0]);
        #pragma unroll
        for (int nt = 0; nt < 4; ++nt) {
            int col = w * 64 + nt * 16 + ln;
            float wgl = bf2f(W16[OFF_WGL + col]);
            #pragma unroll
            for (int r = 0; r < 4; ++r) {
                int row = quad * 4 + r;
                float mrow = mask[m0 + row];
                float logit = acc[nt][r] + mrow * wgl;
                float gate = mrow / (1.0f + __expf(-logit));
                float corr = bf2f(Clds[row * 264 + col]);
                tileB[col * 24 + row] = f2bf(trs * gate * corr);
            }
        }
    }
    __syncthreads();

    // ---- store: out[b,ch,p] = x + delta (256 ch x 16 pos) ----
    #pragma unroll
    for (int i = 0; i < 2; ++i) {
        int idx = tid + i * 256;
        int ch = idx >> 1, p8 = (idx & 1) * 8;
        bf16x8 d = *(const bf16x8*)&tileB[ch * 24 + p8];
        size_t o = ((size_t)b * CC + ch) * NN + p0l + p8;
        float4 x0 = *(const float4*)&x[o];
        float4 x1 = *(const float4*)&x[o + 4];
        float4 o0, o1;
        o0.x = x0.x + bf2f(d[0]); o0.y = x0.y + bf2f(d[1]);
        o0.z = x0.z + bf2f(d[2]); o0.w = x0.w + bf2f(d[3]);
        o1.x = x1.x + bf2f(d[4]); o1.y = x1.y + bf2f(d[5]);
        o1.z = x1.z + bf2f(d[6]); o1.w = x1.w + bf2f(d[7]);
        *(float4*)&out[o] = o0;
        *(float4*)&out[o + 4] = o1;
    }
}

// ---------------------------------------------------------------------------
extern "C" void kernel_launch(void* const* d_in, const int* in_sizes, int n_in,
                              void* d_out, int out_size, void* d_ws, size_t ws_size,
                              hipStream_t stream) {
    const float* x     = (const float*)d_in[0];
    const float* mask  = (const float*)d_in[1];
    const float* gamma = (const float*)d_in[2];
    const float* beta  = (const float*)d_in[3];
    const float* wq    = (const float*)d_in[4];
    const float* wk    = (const float*)d_in[5];
    const float* wv    = (const float*)d_in[6];
    const float* w_out = (const float*)d_in[7];
    const float* w_qm  = (const float*)d_in[8];
    const float* wd1   = (const float*)d_in[9];
    const float* wd2   = (const float*)d_in[10];
    const float* wg    = (const float*)d_in[11];
    const float* rs    = (const float*)d_in[12];
    float* out = (float*)d_out;

    const size_t NC = (size_t)NTOT * CC;
    const size_t NE = (size_t)NTOT * EE;
    short* Xn16  = (short*)d_ws;        // NC
    short* Xt16  = Xn16 + NC;           // NC
    short* Q16   = Xt16 + NC;           // NE
    short* K16   = Q16 + NE;            // NE
    short* V16t  = K16 + NE;            // NC
    short* W16   = V16t + NC;           // W16_TOTAL
    short* Opart = W16 + W16_TOTAL;     // 4*NC
    float* Lpart = (float*)(Opart + 4 * NC);   // 4*NTOT f32
    // ~66 MB total

    wconv_kernel<<<(W16_TOTAL / 4 + 255) / 256, 256, 0, stream>>>(wq, wk, wv, w_out,
                                                                  wd1, wd2, wg, W16);
    lnproj_kernel<<<1024, 256, 0, stream>>>(x, gamma, beta, W16, mask, w_qm,
                                            Xt16, Xn16, Q16, K16, V16t);
    attn_kernel<<<1024, 256, 0, stream>>>(Q16, K16, V16t, mask, Opart, Lpart);
    epi_kernel<<<1024, 256, 0, stream>>>(Opart, Lpart, W16, Xt16, Xn16, mask,
                                         rs, x, out);
}

// Round 13
// 289.020 us; speedup vs baseline: 1.0168x; 1.0076x over previous
//
#include <hip/hip_runtime.h>
#include <hip/hip_bf16.h>
#include <math.h>

// Problem constants
#define BB 4
#define CC 256
#define NN 4096          // H*W
#define EE 96
#define NTOT (BB*NN)     // 16384 rows

typedef __attribute__((ext_vector_type(8))) short bf16x8;
typedef __attribute__((ext_vector_type(4))) float f32x4;

// NATIVE fp32->bf16 (gfx950 HW convert; compiler pairs into v_cvt_pk_bf16_f32).
__device__ __forceinline__ short f2bf(float x) {
    __hip_bfloat16 h = __float2bfloat16(x);
    return *reinterpret_cast<short*>(&h);
}
__device__ __forceinline__ float bf2f(short s) {
    unsigned int u = ((unsigned int)(unsigned short)s) << 16;
    float f;
    __builtin_memcpy(&f, &u, 4);
    return f;
}
__device__ __forceinline__ float gelu_exact(float v) {
    return 0.5f * v * (1.0f + erff(v * 0.70710678118654752f));
}
// async global->LDS, 16B per lane; LDS dest = uniform base + lane*16
__device__ __forceinline__ void gld16(void* lds, const void* g) {
    __builtin_amdgcn_global_load_lds(
        (const __attribute__((address_space(1))) unsigned int*)g,
        (__attribute__((address_space(3))) unsigned int*)lds, 16, 0, 0);
}

// Weight arena offsets (shorts). wg split into 256-stride matrix + last col.
#define OFF_WQ  0
#define OFF_WK  24576
#define OFF_WV  49152
#define OFF_WO  114688
#define OFF_WD1 180224
#define OFF_WD2 311296
#define OFF_WG  376832
#define OFF_WGL 442368
#define W16_TOTAL 442624

// ---------------------------------------------------------------------------
// Kernel 0: weight fp32 -> bf16 converter. 4 elements/thread + short4 store.
// ---------------------------------------------------------------------------
__global__ void wconv_kernel(const float* __restrict__ wq, const float* __restrict__ wk,
                             const float* __restrict__ wv, const float* __restrict__ wo,
                             const float* __restrict__ wd1, const float* __restrict__ wd2,
                             const float* __restrict__ wg, short* __restrict__ W16) {
    int i0 = (blockIdx.x * 256 + threadIdx.x) * 4;
    if (i0 >= W16_TOTAL) return;
    short4 o;
    #pragma unroll
    for (int j = 0; j < 4; ++j) {
        int i = i0 + j;
        float v;
        if      (i < OFF_WK)  v = wq[i];
        else if (i < OFF_WV)  v = wk[i - OFF_WK];
        else if (i < OFF_WO)  v = wv[i - OFF_WV];
        else if (i < OFF_WD1) v = wo[i - OFF_WO];
        else if (i < OFF_WD2) v = wd1[i - OFF_WD1];
        else if (i < OFF_WG)  v = wd2[i - OFF_WD2];
        else if (i < OFF_WGL) { int l = i - OFF_WG; v = wg[(l >> 8) * 257 + (l & 255)]; }
        else                  v = wg[(i - OFF_WGL) * 257 + 256];
        ((short*)&o)[j] = f2bf(v);
    }
    *(short4*)&W16[i0] = o;
}

// ---------------------------------------------------------------------------
// Kernel 1: fused LayerNorm + Q/K/V projections. v3 kept (16 rows/block,
// grid 1024, 4 blocks/CU, wave-specialized proj, LDS-resident A-frags,
// lgkm-only mid barriers).
// ---------------------------------------------------------------------------
__global__ __launch_bounds__(256) void lnproj_kernel(
    const float* __restrict__ x, const float* __restrict__ gamma,
    const float* __restrict__ beta, const short* __restrict__ W16,
    const float* __restrict__ mask, const float* __restrict__ w_qm,
    short* __restrict__ Xt16, short* __restrict__ Xn16,
    short* __restrict__ Q16, short* __restrict__ K16,
    short* __restrict__ V16t)
{
    __shared__ char ldsbuf[17408];            // fp32 tile 256x17 | later Vt 256x24 b16
    float* tile = (float*)ldsbuf;
    short* Vt   = (short*)ldsbuf;
    __shared__ short Xn_lds[16 * 264];        // proj A-frags (normed)
    __shared__ short Xt_lds[16 * 264];        // proj A-frags (raw x)
    __shared__ float psum[16][16], psq[16][16];
    __shared__ float mu_s[16], rs_s[16];
    __shared__ float gs[256], bs[256];

    const int tid = threadIdx.x;
    const int w = tid >> 6, lane = tid & 63, ln = lane & 15, quad = lane >> 4;
    const int b  = blockIdx.x >> 8;
    const int p0 = (blockIdx.x & 255) * 16;
    const int m0 = blockIdx.x * 16;           // global row base (= b*NN + p0)
    const float* xb = x + (size_t)b * CC * NN;

    // ---------------- ln phase ----------------
    gs[tid] = gamma[tid];
    bs[tid] = beta[tid];
    #pragma unroll
    for (int i = 0; i < 4; ++i) {
        int idx = tid + i * 256;
        int c = idx >> 2, p4 = (idx & 3) * 4;
        float4 v = *(const float4*)&xb[(size_t)c * NN + p0 + p4];
        tile[c * 17 + p4]     = v.x;
        tile[c * 17 + p4 + 1] = v.y;
        tile[c * 17 + p4 + 2] = v.z;
        tile[c * 17 + p4 + 3] = v.w;
    }
    __syncthreads();
    {
        int col = tid & 15, part = tid >> 4;   // 16 parts x 16 positions
        float s = 0.f, sq = 0.f;
        for (int r = part * 16; r < part * 16 + 16; ++r) {
            float v = tile[r * 17 + col];
            s += v; sq += v * v;
        }
        psum[part][col] = s; psq[part][col] = sq;
    }
    __syncthreads();
    if (tid < 16) {
        float S = 0.f, SQ = 0.f;
        #pragma unroll
        for (int j = 0; j < 16; ++j) { S += psum[j][tid]; SQ += psq[j][tid]; }
        float mu = S / 256.0f;
        float var = SQ / 256.0f - mu * mu;
        mu_s[tid] = mu;
        rs_s[tid] = rsqrtf(var + 1e-5f);
    }
    __syncthreads();
    #pragma unroll
    for (int i = 0; i < 2; ++i) {
        int idx = tid + i * 256;
        int p = idx >> 5, c8 = (idx & 31) * 8;
        float mu = mu_s[p], rcp = rs_s[p];
        bf16x8 xt, xn;
        #pragma unroll
        for (int j = 0; j < 8; ++j) {
            float v = tile[(c8 + j) * 17 + p];
            float n = (v - mu) * rcp * gs[c8 + j] + bs[c8 + j];
            xt[j] = f2bf(v); xn[j] = f2bf(n);
        }
        size_t o = (size_t)(m0 + p) * CC + c8;
        *(bf16x8*)&Xt16[o] = xt;              // for epi (in flight past barrier)
        *(bf16x8*)&Xn16[o] = xn;              // for epi
        *(bf16x8*)&Xt_lds[p * 264 + c8] = xt; // for proj (LDS, on-chip)
        *(bf16x8*)&Xn_lds[p * 264 + c8] = xn;
    }
    // lgkm-only barrier: LDS tiles visible; fp32-tile reads retired (Vt
    // overlay safe). Global Xt16/Xn16 stores stay in flight.
    asm volatile("s_waitcnt lgkmcnt(0)" ::: "memory");
    __builtin_amdgcn_s_barrier();
    __builtin_amdgcn_sched_barrier(0);

    // ---------------- proj phase (wave-specialized, A-frags from LDS) ------
    if (w < 2) {
        // ---- w0: Q, w1: K — 16 rows x 96 cols, wave-local norm ----
        const bool isQ = (w == 0);
        const int woff = isQ ? OFF_WQ : OFF_WK;

        f32x4 acc[6];
        #pragma unroll
        for (int i = 0; i < 6; ++i) acc[i] = (f32x4){0.f, 0.f, 0.f, 0.f};

        #pragma unroll
        for (int kt = 0; kt < 8; ++kt) {
            bf16x8 af = *(const bf16x8*)&Xn_lds[ln * 264 + kt * 32 + quad * 8];
            #pragma unroll
            for (int nt = 0; nt < 6; ++nt) {
                bf16x8 bf = *(const bf16x8*)&W16[woff + (size_t)(nt * 16 + ln) * 256 + kt * 32 + quad * 8];
                acc[nt] = __builtin_amdgcn_mfma_f32_16x16x32_bf16(af, bf, acc[nt], 0, 0, 0);
            }
        }

        short* outp = isQ ? Q16 : K16;
        #pragma unroll
        for (int r = 0; r < 4; ++r) {
            int row = m0 + quad * 4 + r;
            float mrow = isQ ? mask[row] : 0.f;
            float vals[6];
            float ss = 0.f;
            #pragma unroll
            for (int nt = 0; nt < 6; ++nt) {
                float v = acc[nt][r];
                if (isQ) v += mrow * w_qm[nt * 16 + ln];
                vals[nt] = v;
                ss += v * v;
            }
            ss += __shfl_xor(ss, 1, 64); ss += __shfl_xor(ss, 2, 64);
            ss += __shfl_xor(ss, 4, 64); ss += __shfl_xor(ss, 8, 64);
            float sc = 1.0f / fmaxf(sqrtf(ss), 1e-12f);
            #pragma unroll
            for (int nt = 0; nt < 6; ++nt)
                outp[(size_t)row * EE + nt * 16 + ln] = f2bf(vals[nt] * sc);
        }
    } else {
        // ---- w2/w3: V projection, 16 rows x 128 cols each ----
        const int wn = w - 2;

        f32x4 acc[8];
        #pragma unroll
        for (int i = 0; i < 8; ++i) acc[i] = (f32x4){0.f, 0.f, 0.f, 0.f};

        #pragma unroll
        for (int kt = 0; kt < 8; ++kt) {
            bf16x8 af = *(const bf16x8*)&Xt_lds[ln * 264 + kt * 32 + quad * 8];
            #pragma unroll
            for (int nt = 0; nt < 8; ++nt) {
                int col = wn * 128 + nt * 16 + ln;
                bf16x8 bf = *(const bf16x8*)&W16[OFF_WV + (size_t)col * 256 + kt * 32 + quad * 8];
                acc[nt] = __builtin_amdgcn_mfma_f32_16x16x32_bf16(af, bf, acc[nt], 0, 0, 0);
            }
        }
        #pragma unroll
        for (int nt = 0; nt < 8; ++nt) {
            int ch = wn * 128 + nt * 16 + ln;
            #pragma unroll
            for (int r = 0; r < 4; ++r)
                Vt[ch * 24 + quad * 4 + r] = f2bf(acc[nt][r]);
        }
    }
    // lgkm-only barrier: Vt writes visible; Q/K global stores stay in flight.
    asm volatile("s_waitcnt lgkmcnt(0)" ::: "memory");
    __builtin_amdgcn_s_barrier();
    __builtin_amdgcn_sched_barrier(0);

    // ---- V16t store: 256 ch x 16 pos ----
    #pragma unroll
    for (int i = 0; i < 2; ++i) {
        int idx = tid + i * 256;
        int ch = idx >> 1, p8 = (idx & 1) * 8;
        *(bf16x8*)&V16t[((size_t)b * CC + ch) * NN + p0 + p8] =
            *(const bf16x8*)&Vt[ch * 24 + p8];
    }
}

// ---------------------------------------------------------------------------
// Kernel 2: MFMA attention, 4-way K-split. v13 = v9 EXACT (94.4us best):
// single barrier/iter, T14 issue-early K DMA, __expf softmax (round-12
// lesson: libm exp2f is NOT the bare v_exp_f32 — VALUBusy 24->31%, +3.6us).
// ---------------------------------------------------------------------------
__global__ __launch_bounds__(256, 4) void attn_kernel(
    const short* __restrict__ Q16, const short* __restrict__ K16,
    const short* __restrict__ V16t, const float* __restrict__ mask,
    short* __restrict__ Opart, float* __restrict__ Lpart)
{
    __shared__ short Ks[2][3072];     // [buf][p 0..11][key 0..31] chunks of 8 shorts
    __shared__ short Ps[2][2560];     // [buf][64 rows][40] (stride-40 padded)

    const int tid = threadIdx.x;
    const int w = tid >> 6, lane = tid & 63, ln = lane & 15, quad = lane >> 4;
    const int bidx = blockIdx.x;
    const int kg = bidx >> 8;                       // 0..3 key group
    const int qg = bidx & 255;
    const int b  = (qg & 7) >> 1;                   // XCD-pinned batch
    const int qt = ((qg >> 3) << 1) | (qg & 1);     // 0..63
    const int q0 = qt * 64;
    const size_t bN = (size_t)b * NN;
    const size_t bCC = (size_t)b * CC;
    const int kbase = kg * 1024;
    const float C1 = 1.02062072615966f;             // 10/sqrt(96)
    const int wbase = w * 64;

    #define STAGEK(buf, kk)                                                         \
        do {                                                                        \
            gld16(&Ks[buf][wbase * 8],                                              \
                  &K16[(bN + (kk) + (tid & 31)) * EE + (tid >> 5) * 8]);            \
            if (w < 2)                                                              \
                gld16(&Ks[buf][(256 + wbase) * 8],                                  \
                      &K16[(bN + (kk) + (tid & 31)) * EE + (8 + (tid >> 5)) * 8]);  \
        } while (0)

    bf16x8 qf[3];
    #pragma unroll
    for (int e = 0; e < 3; ++e)
        qf[e] = *(const bf16x8*)&Q16[(bN + q0 + w * 16 + ln) * EE + e * 32 + quad * 8];

    f32x4 acc[4][4];
    #pragma unroll
    for (int mt = 0; mt < 4; ++mt)
        #pragma unroll
        for (int nt = 0; nt < 4; ++nt) acc[mt][nt] = (f32x4){0.f, 0.f, 0.f, 0.f};
    float lsum[4] = {0.f, 0.f, 0.f, 0.f};

    // prologue: K(0)->Ks[0], K(1)->Ks[1]; full drain outside the loop.
    STAGEK(0, kbase);
    STAGEK(1, kbase + 32);
    __syncthreads();

    for (int it = 0; it < 32; ++it) {
        const int k0 = kbase + it * 32;
        const int cur = it & 1;

        // V fragments + mask direct global->reg (QK+softmax of cover).
        bf16x8 vf[4];
        #pragma unroll
        for (int nt = 0; nt < 4; ++nt)
            vf[nt] = *(const bf16x8*)&V16t[(bCC + wbase + nt * 16 + ln) * NN + k0 + quad * 8];
        const float mk0 = mask[bN + k0 + ln];
        const float mk1 = mask[bN + k0 + 16 + ln];

        // ---- S = Q K^T (K from LDS buffer cur; landed a full period ago) ----
        f32x4 s0 = (f32x4){0.f,0.f,0.f,0.f}, s1 = s0;
        __builtin_amdgcn_s_setprio(1);
        #pragma unroll
        for (int e = 0; e < 3; ++e) {
            bf16x8 kf0 = *(const bf16x8*)&Ks[cur][((e * 4 + quad) * 32 + ln) * 8];
            bf16x8 kf1 = *(const bf16x8*)&Ks[cur][((e * 4 + quad) * 32 + 16 + ln) * 8];
            s0 = __builtin_amdgcn_mfma_f32_16x16x32_bf16(qf[e], kf0, s0, 0, 0, 0);
            s1 = __builtin_amdgcn_mfma_f32_16x16x32_bf16(qf[e], kf1, s1, 0, 0, 0);
        }
        __builtin_amdgcn_s_setprio(0);
        const bool z0 = mk0 >= 0.5f;
        const bool z1 = mk1 >= 0.5f;
        #pragma unroll
        for (int r = 0; r < 4; ++r) {
            float p0 = z0 ? 0.f : __expf(fmaf(s0[r], C1, -C1));
            float p1 = z1 ? 0.f : __expf(fmaf(s1[r], C1, -C1));
            lsum[r] += p0 + p1;
            Ps[cur][(w * 16 + quad * 4 + r) * 40 + ln]      = f2bf(p0);
            Ps[cur][(w * 16 + quad * 4 + r) * 40 + 16 + ln] = f2bf(p1);
        }
        // ---- the ONE barrier: publishes Ps(cur); drains K(it+1) DMA (issued
        // post-barrier(it-1), ~full period of cover) and this iter's vf/mask.
        asm volatile("s_waitcnt vmcnt(0) lgkmcnt(0)" ::: "memory");
        __builtin_amdgcn_s_barrier();
        __builtin_amdgcn_sched_barrier(0);

        // ---- T14 issue-early: K(it+2) into Ks[cur] — buffer just freed.
        if (it + 2 < 32) STAGEK(cur, k0 + 64);

        // ---- PV: all 64 q x this wave's 64 channels; V from registers ----
        __builtin_amdgcn_s_setprio(1);
        #pragma unroll
        for (int mt = 0; mt < 4; ++mt) {
            bf16x8 pf = *(const bf16x8*)&Ps[cur][(mt * 16 + ln) * 40 + quad * 8];
            #pragma unroll
            for (int nt = 0; nt < 4; ++nt)
                acc[mt][nt] = __builtin_amdgcn_mfma_f32_16x16x32_bf16(pf, vf[nt], acc[mt][nt], 0, 0, 0);
        }
        __builtin_amdgcn_s_setprio(0);
        // no end-of-iter barrier: next iter writes the OTHER Ps buffer, and
        // Ks[cur^1] (next QK source) was drained at this iter's barrier.
    }
    #undef STAGEK

    // ---- epilogue: partial l and partial O ----
    #pragma unroll
    for (int r = 0; r < 4; ++r) {
        float l = lsum[r];
        l += __shfl_xor(l, 1, 64); l += __shfl_xor(l, 2, 64);
        l += __shfl_xor(l, 4, 64); l += __shfl_xor(l, 8, 64);
        if (ln == 0)
            Lpart[(size_t)kg * NTOT + bN + q0 + w * 16 + quad * 4 + r] = l;
    }
    #pragma unroll
    for (int mt = 0; mt < 4; ++mt)
        #pragma unroll
        for (int nt = 0; nt < 4; ++nt)
            #pragma unroll
            for (int r = 0; r < 4; ++r)
                Opart[((size_t)kg * NTOT + bN + q0 + mt * 16 + quad * 4 + r) * 256
                      + wbase + nt * 16 + ln] = f2bf(acc[mt][nt][r]);
}

// ---------------------------------------------------------------------------
// Kernel 3: mega-fused epilogue. v8 kept (3-region rotation, 6 barriers,
// hoisted input loads, native f2bf).
// ---------------------------------------------------------------------------
__global__ __launch_bounds__(256, 4) void epi_kernel(
    const short* __restrict__ Opart, const float* __restrict__ Lpart,
    const short* __restrict__ W16, const short* __restrict__ Xt16,
    const short* __restrict__ Xn16, const float* __restrict__ mask,
    const float* __restrict__ rs, const float* __restrict__ x,
    float* __restrict__ out)
{
    __shared__ char lds[37696];
    short* Olds  = (short*)lds;              // region A: 16 x 264 (P1-P2)
    short* Clds  = (short*)lds;              // region A reuse (P4-P5)
    short* Dlds  = (short*)(lds + 8448);     // region B: 16 x 528 (P1-P3)
    short* Hlds  = (short*)(lds + 25344);    // region C: 16 x 264 (P3-P4)
    short* tileB = (short*)(lds + 25344);    // region C reuse: 256 x 24 (P5+)
    float* lsh   = (float*)(lds + 37632);    // 16

    const int tid = threadIdx.x;
    const int w = tid >> 6, lane = tid & 63, ln = lane & 15, quad = lane >> 4;
    const int m0 = blockIdx.x * 16;
    const int b = m0 >> 12, p0l = m0 & 4095;

    // ---- hoisted input loads (pure inputs; overlap the barrier drain) ----
    bf16x8 ha0[2], ha1[2], ha2[2], ha3[2], hxn[2];
    float  hmq[2];
    #pragma unroll
    for (int i = 0; i < 2; ++i) {
        int idx = tid + i * 256;
        int q = idx >> 5, ch8 = (idx & 31) * 8;
        size_t base = (size_t)(m0 + q) * 256 + ch8;
        ha0[i] = *(const bf16x8*)&Opart[base];
        ha1[i] = *(const bf16x8*)&Opart[(size_t)NTOT * 256 + base];
        ha2[i] = *(const bf16x8*)&Opart[(size_t)2 * NTOT * 256 + base];
        ha3[i] = *(const bf16x8*)&Opart[(size_t)3 * NTOT * 256 + base];
        hxn[i] = *(const bf16x8*)&Xn16[base];
        hmq[i] = mask[m0 + q];
    }
    short xtv[4][4];
    #pragma unroll
    for (int nt = 0; nt < 4; ++nt)
        #pragma unroll
        for (int r = 0; r < 4; ++r)
            xtv[nt][r] = Xt16[(size_t)(m0 + quad * 4 + r) * 256 + (w * 64 + nt * 16 + ln)];

    if (tid < 16) {
        int g = m0 + tid;
        lsh[tid] = 1.0f / (Lpart[g] + Lpart[NTOT + g] + Lpart[2 * NTOT + g] + Lpart[3 * NTOT + g]);
    }
    __syncthreads();

    // ---- P1: combine partials (from hoisted regs) -> Olds; Xnm -> Dlds ----
    #pragma unroll
    for (int i = 0; i < 2; ++i) {
        int idx = tid + i * 256;
        int q = idx >> 5, ch8 = (idx & 31) * 8;
        float linv = lsh[q];
        bf16x8 o;
        #pragma unroll
        for (int e = 0; e < 8; ++e)
            o[e] = f2bf((bf2f(ha0[i][e]) + bf2f(ha1[i][e]) + bf2f(ha2[i][e]) + bf2f(ha3[i][e])) * linv);
        *(bf16x8*)&Olds[q * 264 + ch8] = o;
        bf16x8 xm;
        #pragma unroll
        for (int e = 0; e < 8; ++e) xm[e] = f2bf(bf2f(hxn[i][e]) * hmq[i]);
        *(bf16x8*)&Dlds[q * 528 + 256 + ch8] = xm;
    }
    __syncthreads();

    // ---- P2: D1 = O@wo^T - Xt (reads A, writes B-lower) ----
    {
        f32x4 acc[4];
        #pragma unroll
        for (int i = 0; i < 4; ++i) acc[i] = (f32x4){0.f, 0.f, 0.f, 0.f};
        #pragma unroll
        for (int kt = 0; kt < 8; ++kt) {
            bf16x8 af = *(const bf16x8*)&Olds[ln * 264 + kt * 32 + quad * 8];
            #pragma unroll
            for (int nt = 0; nt < 4; ++nt) {
                int col = w * 64 + nt * 16 + ln;
                bf16x8 bf = *(const bf16x8*)&W16[OFF_WO + (size_t)col * 256 + kt * 32 + quad * 8];
                acc[nt] = __builtin_amdgcn_mfma_f32_16x16x32_bf16(af, bf, acc[nt], 0, 0, 0);
            }
        }
        #pragma unroll
        for (int nt = 0; nt < 4; ++nt) {
            int col = w * 64 + nt * 16 + ln;
            #pragma unroll
            for (int r = 0; r < 4; ++r) {
                int row = quad * 4 + r;
                float v = acc[nt][r] - bf2f(xtv[nt][r]);
                Dlds[row * 528 + col] = f2bf(v);
            }
        }
    }
    __syncthreads();

    // ---- P3: Hid = gelu([D1|Xnm] @ wd1^T) (reads B, writes C) ----
    {
        f32x4 acc[4];
        #pragma unroll
        for (int i = 0; i < 4; ++i) acc[i] = (f32x4){0.f, 0.f, 0.f, 0.f};
        #pragma unroll
        for (int kt = 0; kt < 16; ++kt) {
            bf16x8 af = *(const bf16x8*)&Dlds[ln * 528 + kt * 32 + quad * 8];
            #pragma unroll
            for (int nt = 0; nt < 4; ++nt) {
                int col = w * 64 + nt * 16 + ln;
                bf16x8 bf = *(const bf16x8*)&W16[OFF_WD1 + (size_t)col * 512 + kt * 32 + quad * 8];
                acc[nt] = __builtin_amdgcn_mfma_f32_16x16x32_bf16(af, bf, acc[nt], 0, 0, 0);
            }
        }
        #pragma unroll
        for (int nt = 0; nt < 4; ++nt) {
            int col = w * 64 + nt * 16 + ln;
            #pragma unroll
            for (int r = 0; r < 4; ++r) {
                int row = quad * 4 + r;
                Hlds[row * 264 + col] = f2bf(gelu_exact(acc[nt][r]));
            }
        }
    }
    __syncthreads();

    // ---- P4: Cor = Hid @ wd2^T (reads C, writes A; A last read in P2) ----
    {
        f32x4 acc[4];
        #pragma unroll
        for (int i = 0; i < 4; ++i) acc[i] = (f32x4){0.f, 0.f, 0.f, 0.f};
        #pragma unroll
        for (int kt = 0; kt < 8; ++kt) {
            bf16x8 af = *(const bf16x8*)&Hlds[ln * 264 + kt * 32 + quad * 8];
            #pragma unroll
            for (int nt = 0; nt < 4; ++nt) {
                int col = w * 64 + nt * 16 + ln;
                bf16x8 bf = *(const bf16x8*)&W16[OFF_WD2 + (size_t)col * 256 + kt * 32 + quad * 8];
                acc[nt] = __builtin_amdgcn_mfma_f32_16x16x32_bf16(af, bf, acc[nt], 0, 0, 0);
            }
        }
        #pragma unroll
        for (int nt = 0; nt < 4; ++nt) {
            int col = w * 64 + nt * 16 + ln;
            #pragma unroll
            for (int r = 0; r < 4; ++r) {
                int row = quad * 4 + r;
                Clds[row * 264 + col] = f2bf(acc[nt][r]);
            }
        }
    }
    __syncthreads();

    // ---- P5: gate GEMM + delta (reads A, writes C; C last read in P4) ----
    {
        f32x4 acc[4];
        #pragma unroll
        for (int i = 0; i < 4; ++i) acc[i] = (f32x4){0.f, 0.f, 0.f, 0.f};
        #pragma unroll
        for (int kt = 0; kt < 8; ++kt) {
            bf16x8 af = *(const bf16x8*)&Clds[ln * 264 + kt * 32 + quad * 8];
            #pragma unroll
            for (int nt = 0; nt < 4; ++nt) {
                int col = w * 64 + nt * 16 + ln;
                bf16x8 bf = *(const bf16x8*)&W16[OFF_WG + (size_t)col * 256 + kt * 32 + quad * 8];
                acc[nt] = __builtin_amdgcn_mfma_f32_16x16x32_bf16(af, bf, acc[nt], 0, 0, 0);
            }
        }
        float trs = tanhf(rs[0]);
        #pragma unroll
        for (int nt = 0; nt < 4; ++nt) {
            int col = w * 64 + nt * 16 + ln;
            float wgl = bf2f(W16[OFF_WGL + col]);
            #pragma unroll
            for (int r = 0; r < 4; ++r) {
                int row = quad * 4 + r;
                float mrow = mask[m0 + row];
                float logit = acc[nt][r] + mrow * wgl;
                float gate = mrow / (1.0f + __expf(-logit));
                float corr = bf2f(Clds[row * 264 + col]);
                tileB[col * 24 + row] = f2bf(trs * gate * corr);
            }
        }
    }
    __syncthreads();

    // ---- store: out[b,ch,p] = x + delta (256 ch x 16 pos) ----
    #pragma unroll
    for (int i = 0; i < 2; ++i) {
        int idx = tid + i * 256;
        int ch = idx >> 1, p8 = (idx & 1) * 8;
        bf16x8 d = *(const bf16x8*)&tileB[ch * 24 + p8];
        size_t o = ((size_t)b * CC + ch) * NN + p0l + p8;
        float4 x0 = *(const float4*)&x[o];
        float4 x1 = *(const float4*)&x[o + 4];
        float4 o0, o1;
        o0.x = x0.x + bf2f(d[0]); o0.y = x0.y + bf2f(d[1]);
        o0.z = x0.z + bf2f(d[2]); o0.w = x0.w + bf2f(d[3]);
        o1.x = x1.x + bf2f(d[4]); o1.y = x1.y + bf2f(d[5]);
        o1.z = x1.z + bf2f(d[6]); o1.w = x1.w + bf2f(d[7]);
        *(float4*)&out[o] = o0;
        *(float4*)&out[o + 4] = o1;
    }
}

// ---------------------------------------------------------------------------
extern "C" void kernel_launch(void* const* d_in, const int* in_sizes, int n_in,
                              void* d_out, int out_size, void* d_ws, size_t ws_size,
                              hipStream_t stream) {
    const float* x     = (const float*)d_in[0];
    const float* mask  = (const float*)d_in[1];
    const float* gamma = (const float*)d_in[2];
    const float* beta  = (const float*)d_in[3];
    const float* wq    = (const float*)d_in[4];
    const float* wk    = (const float*)d_in[5];
    const float* wv    = (const float*)d_in[6];
    const float* w_out = (const float*)d_in[7];
    const float* w_qm  = (const float*)d_in[8];
    const float* wd1   = (const float*)d_in[9];
    const float* wd2   = (const float*)d_in[10];
    const float* wg    = (const float*)d_in[11];
    const float* rs    = (const float*)d_in[12];
    float* out = (float*)d_out;

    const size_t NC = (size_t)NTOT * CC;
    const size_t NE = (size_t)NTOT * EE;
    short* Xn16  = (short*)d_ws;        // NC
    short* Xt16  = Xn16 + NC;           // NC
    short* Q16   = Xt16 + NC;           // NE
    short* K16   = Q16 + NE;            // NE
    short* V16t  = K16 + NE;            // NC
    short* W16   = V16t + NC;           // W16_TOTAL
    short* Opart = W16 + W16_TOTAL;     // 4*NC
    float* Lpart = (float*)(Opart + 4 * NC);   // 4*NTOT f32
    // ~66 MB total

    wconv_kernel<<<(W16_TOTAL / 4 + 255) / 256, 256, 0, stream>>>(wq, wk, wv, w_out,
                                                                  wd1, wd2, wg, W16);
    lnproj_kernel<<<1024, 256, 0, stream>>>(x, gamma, beta, W16, mask, w_qm,
                                            Xt16, Xn16, Q16, K16, V16t);
    attn_kernel<<<1024, 256, 0, stream>>>(Q16, K16, V16t, mask, Opart, Lpart);
    epi_kernel<<<1024, 256, 0, stream>>>(Opart, Lpart, W16, Xt16, Xn16, mask,
                                         rs, x, out);
}

// Round 14
// 288.113 us; speedup vs baseline: 1.0200x; 1.0031x over previous
//
#include <hip/hip_runtime.h>
#include <hip/hip_bf16.h>
#include <math.h>

// Problem constants
#define BB 4
#define CC 256
#define NN 4096          // H*W
#define EE 96
#define NTOT (BB*NN)     // 16384 rows

typedef __attribute__((ext_vector_type(8))) short bf16x8;
typedef __attribute__((ext_vector_type(4))) float f32x4;

// NATIVE fp32->bf16 (gfx950 HW convert; compiler pairs into v_cvt_pk_bf16_f32).
__device__ __forceinline__ short f2bf(float x) {
    __hip_bfloat16 h = __float2bfloat16(x);
    return *reinterpret_cast<short*>(&h);
}
__device__ __forceinline__ float bf2f(short s) {
    unsigned int u = ((unsigned int)(unsigned short)s) << 16;
    float f;
    __builtin_memcpy(&f, &u, 4);
    return f;
}
__device__ __forceinline__ float gelu_exact(float v) {
    return 0.5f * v * (1.0f + erff(v * 0.70710678118654752f));
}
// async global->LDS, 16B per lane; LDS dest = uniform base + lane*16
__device__ __forceinline__ void gld16(void* lds, const void* g) {
    __builtin_amdgcn_global_load_lds(
        (const __attribute__((address_space(1))) unsigned int*)g,
        (__attribute__((address_space(3))) unsigned int*)lds, 16, 0, 0);
}

// Weight arena offsets (shorts). wg split into 256-stride matrix + last col.
#define OFF_WQ  0
#define OFF_WK  24576
#define OFF_WV  49152
#define OFF_WO  114688
#define OFF_WD1 180224
#define OFF_WD2 311296
#define OFF_WG  376832
#define OFF_WGL 442368
#define W16_TOTAL 442624

// ---------------------------------------------------------------------------
// Kernel 0: weight fp32 -> bf16 converter. 4 elements/thread + short4 store.
// ---------------------------------------------------------------------------
__global__ void wconv_kernel(const float* __restrict__ wq, const float* __restrict__ wk,
                             const float* __restrict__ wv, const float* __restrict__ wo,
                             const float* __restrict__ wd1, const float* __restrict__ wd2,
                             const float* __restrict__ wg, short* __restrict__ W16) {
    int i0 = (blockIdx.x * 256 + threadIdx.x) * 4;
    if (i0 >= W16_TOTAL) return;
    short4 o;
    #pragma unroll
    for (int j = 0; j < 4; ++j) {
        int i = i0 + j;
        float v;
        if      (i < OFF_WK)  v = wq[i];
        else if (i < OFF_WV)  v = wk[i - OFF_WK];
        else if (i < OFF_WO)  v = wv[i - OFF_WV];
        else if (i < OFF_WD1) v = wo[i - OFF_WO];
        else if (i < OFF_WD2) v = wd1[i - OFF_WD1];
        else if (i < OFF_WG)  v = wd2[i - OFF_WD2];
        else if (i < OFF_WGL) { int l = i - OFF_WG; v = wg[(l >> 8) * 257 + (l & 255)]; }
        else                  v = wg[(i - OFF_WGL) * 257 + 256];
        ((short*)&o)[j] = f2bf(v);
    }
    *(short4*)&W16[i0] = o;
}

// ---------------------------------------------------------------------------
// Kernel 1: fused LayerNorm + Q/K/V projections. v3 kept (16 rows/block,
// grid 1024, 4 blocks/CU, wave-specialized proj, LDS-resident A-frags,
// lgkm-only mid barriers).
// ---------------------------------------------------------------------------
__global__ __launch_bounds__(256) void lnproj_kernel(
    const float* __restrict__ x, const float* __restrict__ gamma,
    const float* __restrict__ beta, const short* __restrict__ W16,
    const float* __restrict__ mask, const float* __restrict__ w_qm,
    short* __restrict__ Xt16, short* __restrict__ Xn16,
    short* __restrict__ Q16, short* __restrict__ K16,
    short* __restrict__ V16t)
{
    __shared__ char ldsbuf[17408];            // fp32 tile 256x17 | later Vt 256x24 b16
    float* tile = (float*)ldsbuf;
    short* Vt   = (short*)ldsbuf;
    __shared__ short Xn_lds[16 * 264];        // proj A-frags (normed)
    __shared__ short Xt_lds[16 * 264];        // proj A-frags (raw x)
    __shared__ float psum[16][16], psq[16][16];
    __shared__ float mu_s[16], rs_s[16];
    __shared__ float gs[256], bs[256];

    const int tid = threadIdx.x;
    const int w = tid >> 6, lane = tid & 63, ln = lane & 15, quad = lane >> 4;
    const int b  = blockIdx.x >> 8;
    const int p0 = (blockIdx.x & 255) * 16;
    const int m0 = blockIdx.x * 16;           // global row base (= b*NN + p0)
    const float* xb = x + (size_t)b * CC * NN;

    // ---------------- ln phase ----------------
    gs[tid] = gamma[tid];
    bs[tid] = beta[tid];
    #pragma unroll
    for (int i = 0; i < 4; ++i) {
        int idx = tid + i * 256;
        int c = idx >> 2, p4 = (idx & 3) * 4;
        float4 v = *(const float4*)&xb[(size_t)c * NN + p0 + p4];
        tile[c * 17 + p4]     = v.x;
        tile[c * 17 + p4 + 1] = v.y;
        tile[c * 17 + p4 + 2] = v.z;
        tile[c * 17 + p4 + 3] = v.w;
    }
    __syncthreads();
    {
        int col = tid & 15, part = tid >> 4;   // 16 parts x 16 positions
        float s = 0.f, sq = 0.f;
        for (int r = part * 16; r < part * 16 + 16; ++r) {
            float v = tile[r * 17 + col];
            s += v; sq += v * v;
        }
        psum[part][col] = s; psq[part][col] = sq;
    }
    __syncthreads();
    if (tid < 16) {
        float S = 0.f, SQ = 0.f;
        #pragma unroll
        for (int j = 0; j < 16; ++j) { S += psum[j][tid]; SQ += psq[j][tid]; }
        float mu = S / 256.0f;
        float var = SQ / 256.0f - mu * mu;
        mu_s[tid] = mu;
        rs_s[tid] = rsqrtf(var + 1e-5f);
    }
    __syncthreads();
    #pragma unroll
    for (int i = 0; i < 2; ++i) {
        int idx = tid + i * 256;
        int p = idx >> 5, c8 = (idx & 31) * 8;
        float mu = mu_s[p], rcp = rs_s[p];
        bf16x8 xt, xn;
        #pragma unroll
        for (int j = 0; j < 8; ++j) {
            float v = tile[(c8 + j) * 17 + p];
            float n = (v - mu) * rcp * gs[c8 + j] + bs[c8 + j];
            xt[j] = f2bf(v); xn[j] = f2bf(n);
        }
        size_t o = (size_t)(m0 + p) * CC + c8;
        *(bf16x8*)&Xt16[o] = xt;              // for epi (in flight past barrier)
        *(bf16x8*)&Xn16[o] = xn;              // for epi
        *(bf16x8*)&Xt_lds[p * 264 + c8] = xt; // for proj (LDS, on-chip)
        *(bf16x8*)&Xn_lds[p * 264 + c8] = xn;
    }
    // lgkm-only barrier: LDS tiles visible; fp32-tile reads retired (Vt
    // overlay safe). Global Xt16/Xn16 stores stay in flight.
    asm volatile("s_waitcnt lgkmcnt(0)" ::: "memory");
    __builtin_amdgcn_s_barrier();
    __builtin_amdgcn_sched_barrier(0);

    // ---------------- proj phase (wave-specialized, A-frags from LDS) ------
    if (w < 2) {
        // ---- w0: Q, w1: K — 16 rows x 96 cols, wave-local norm ----
        const bool isQ = (w == 0);
        const int woff = isQ ? OFF_WQ : OFF_WK;

        f32x4 acc[6];
        #pragma unroll
        for (int i = 0; i < 6; ++i) acc[i] = (f32x4){0.f, 0.f, 0.f, 0.f};

        #pragma unroll
        for (int kt = 0; kt < 8; ++kt) {
            bf16x8 af = *(const bf16x8*)&Xn_lds[ln * 264 + kt * 32 + quad * 8];
            #pragma unroll
            for (int nt = 0; nt < 6; ++nt) {
                bf16x8 bf = *(const bf16x8*)&W16[woff + (size_t)(nt * 16 + ln) * 256 + kt * 32 + quad * 8];
                acc[nt] = __builtin_amdgcn_mfma_f32_16x16x32_bf16(af, bf, acc[nt], 0, 0, 0);
            }
        }

        short* outp = isQ ? Q16 : K16;
        #pragma unroll
        for (int r = 0; r < 4; ++r) {
            int row = m0 + quad * 4 + r;
            float mrow = isQ ? mask[row] : 0.f;
            float vals[6];
            float ss = 0.f;
            #pragma unroll
            for (int nt = 0; nt < 6; ++nt) {
                float v = acc[nt][r];
                if (isQ) v += mrow * w_qm[nt * 16 + ln];
                vals[nt] = v;
                ss += v * v;
            }
            ss += __shfl_xor(ss, 1, 64); ss += __shfl_xor(ss, 2, 64);
            ss += __shfl_xor(ss, 4, 64); ss += __shfl_xor(ss, 8, 64);
            float sc = 1.0f / fmaxf(sqrtf(ss), 1e-12f);
            #pragma unroll
            for (int nt = 0; nt < 6; ++nt)
                outp[(size_t)row * EE + nt * 16 + ln] = f2bf(vals[nt] * sc);
        }
    } else {
        // ---- w2/w3: V projection, 16 rows x 128 cols each ----
        const int wn = w - 2;

        f32x4 acc[8];
        #pragma unroll
        for (int i = 0; i < 8; ++i) acc[i] = (f32x4){0.f, 0.f, 0.f, 0.f};

        #pragma unroll
        for (int kt = 0; kt < 8; ++kt) {
            bf16x8 af = *(const bf16x8*)&Xt_lds[ln * 264 + kt * 32 + quad * 8];
            #pragma unroll
            for (int nt = 0; nt < 8; ++nt) {
                int col = wn * 128 + nt * 16 + ln;
                bf16x8 bf = *(const bf16x8*)&W16[OFF_WV + (size_t)col * 256 + kt * 32 + quad * 8];
                acc[nt] = __builtin_amdgcn_mfma_f32_16x16x32_bf16(af, bf, acc[nt], 0, 0, 0);
            }
        }
        #pragma unroll
        for (int nt = 0; nt < 8; ++nt) {
            int ch = wn * 128 + nt * 16 + ln;
            #pragma unroll
            for (int r = 0; r < 4; ++r)
                Vt[ch * 24 + quad * 4 + r] = f2bf(acc[nt][r]);
        }
    }
    // lgkm-only barrier: Vt writes visible; Q/K global stores stay in flight.
    asm volatile("s_waitcnt lgkmcnt(0)" ::: "memory");
    __builtin_amdgcn_s_barrier();
    __builtin_amdgcn_sched_barrier(0);

    // ---- V16t store: 256 ch x 16 pos ----
    #pragma unroll
    for (int i = 0; i < 2; ++i) {
        int idx = tid + i * 256;
        int ch = idx >> 1, p8 = (idx & 1) * 8;
        *(bf16x8*)&V16t[((size_t)b * CC + ch) * NN + p0 + p8] =
            *(const bf16x8*)&Vt[ch * 24 + p8];
    }
}

// ---------------------------------------------------------------------------
// Kernel 2: MFMA attention, 4-way K-split. v14 = v9 schedule (95.4us) +
// vectorized Opart epilogue: acc transposed through the now-dead Ps LDS
// (per-mt 16x264 chunk) -> 8 coalesced global_store_dwordx4 per thread
// instead of 64 scalar 2B stores (4 discontiguous 32B segments each).
// ---------------------------------------------------------------------------
__global__ __launch_bounds__(256, 4) void attn_kernel(
    const short* __restrict__ Q16, const short* __restrict__ K16,
    const short* __restrict__ V16t, const float* __restrict__ mask,
    short* __restrict__ Opart, float* __restrict__ Lpart)
{
    __shared__ short Ks[2][3072];     // [buf][p 0..11][key 0..31] chunks of 8 shorts
    __shared__ short Ps[2][2560];     // [buf][64 rows][40] (stride-40 padded)

    const int tid = threadIdx.x;
    const int w = tid >> 6, lane = tid & 63, ln = lane & 15, quad = lane >> 4;
    const int bidx = blockIdx.x;
    const int kg = bidx >> 8;                       // 0..3 key group
    const int qg = bidx & 255;
    const int b  = (qg & 7) >> 1;                   // XCD-pinned batch
    const int qt = ((qg >> 3) << 1) | (qg & 1);     // 0..63
    const int q0 = qt * 64;
    const size_t bN = (size_t)b * NN;
    const size_t bCC = (size_t)b * CC;
    const int kbase = kg * 1024;
    const float C1 = 1.02062072615966f;             // 10/sqrt(96)
    const int wbase = w * 64;

    #define STAGEK(buf, kk)                                                         \
        do {                                                                        \
            gld16(&Ks[buf][wbase * 8],                                              \
                  &K16[(bN + (kk) + (tid & 31)) * EE + (tid >> 5) * 8]);            \
            if (w < 2)                                                              \
                gld16(&Ks[buf][(256 + wbase) * 8],                                  \
                      &K16[(bN + (kk) + (tid & 31)) * EE + (8 + (tid >> 5)) * 8]);  \
        } while (0)

    bf16x8 qf[3];
    #pragma unroll
    for (int e = 0; e < 3; ++e)
        qf[e] = *(const bf16x8*)&Q16[(bN + q0 + w * 16 + ln) * EE + e * 32 + quad * 8];

    f32x4 acc[4][4];
    #pragma unroll
    for (int mt = 0; mt < 4; ++mt)
        #pragma unroll
        for (int nt = 0; nt < 4; ++nt) acc[mt][nt] = (f32x4){0.f, 0.f, 0.f, 0.f};
    float lsum[4] = {0.f, 0.f, 0.f, 0.f};

    // prologue: K(0)->Ks[0], K(1)->Ks[1]; full drain outside the loop.
    STAGEK(0, kbase);
    STAGEK(1, kbase + 32);
    __syncthreads();

    for (int it = 0; it < 32; ++it) {
        const int k0 = kbase + it * 32;
        const int cur = it & 1;

        // V fragments + mask direct global->reg (QK+softmax of cover).
        bf16x8 vf[4];
        #pragma unroll
        for (int nt = 0; nt < 4; ++nt)
            vf[nt] = *(const bf16x8*)&V16t[(bCC + wbase + nt * 16 + ln) * NN + k0 + quad * 8];
        const float mk0 = mask[bN + k0 + ln];
        const float mk1 = mask[bN + k0 + 16 + ln];

        // ---- S = Q K^T (K from LDS buffer cur; landed a full period ago) ----
        f32x4 s0 = (f32x4){0.f,0.f,0.f,0.f}, s1 = s0;
        __builtin_amdgcn_s_setprio(1);
        #pragma unroll
        for (int e = 0; e < 3; ++e) {
            bf16x8 kf0 = *(const bf16x8*)&Ks[cur][((e * 4 + quad) * 32 + ln) * 8];
            bf16x8 kf1 = *(const bf16x8*)&Ks[cur][((e * 4 + quad) * 32 + 16 + ln) * 8];
            s0 = __builtin_amdgcn_mfma_f32_16x16x32_bf16(qf[e], kf0, s0, 0, 0, 0);
            s1 = __builtin_amdgcn_mfma_f32_16x16x32_bf16(qf[e], kf1, s1, 0, 0, 0);
        }
        __builtin_amdgcn_s_setprio(0);
        const bool z0 = mk0 >= 0.5f;
        const bool z1 = mk1 >= 0.5f;
        #pragma unroll
        for (int r = 0; r < 4; ++r) {
            float p0 = z0 ? 0.f : __expf(fmaf(s0[r], C1, -C1));
            float p1 = z1 ? 0.f : __expf(fmaf(s1[r], C1, -C1));
            lsum[r] += p0 + p1;
            Ps[cur][(w * 16 + quad * 4 + r) * 40 + ln]      = f2bf(p0);
            Ps[cur][(w * 16 + quad * 4 + r) * 40 + 16 + ln] = f2bf(p1);
        }
        // ---- the ONE barrier: publishes Ps(cur); drains K(it+1) DMA (issued
        // post-barrier(it-1), ~full period of cover) and this iter's vf/mask.
        asm volatile("s_waitcnt vmcnt(0) lgkmcnt(0)" ::: "memory");
        __builtin_amdgcn_s_barrier();
        __builtin_amdgcn_sched_barrier(0);

        // ---- T14 issue-early: K(it+2) into Ks[cur] — buffer just freed.
        if (it + 2 < 32) STAGEK(cur, k0 + 64);

        // ---- PV: all 64 q x this wave's 64 channels; V from registers ----
        __builtin_amdgcn_s_setprio(1);
        #pragma unroll
        for (int mt = 0; mt < 4; ++mt) {
            bf16x8 pf = *(const bf16x8*)&Ps[cur][(mt * 16 + ln) * 40 + quad * 8];
            #pragma unroll
            for (int nt = 0; nt < 4; ++nt)
                acc[mt][nt] = __builtin_amdgcn_mfma_f32_16x16x32_bf16(pf, vf[nt], acc[mt][nt], 0, 0, 0);
        }
        __builtin_amdgcn_s_setprio(0);
        // no end-of-iter barrier: next iter writes the OTHER Ps buffer, and
        // Ks[cur^1] (next QK source) was drained at this iter's barrier.
    }
    #undef STAGEK

    // ---- epilogue: partial l ----
    #pragma unroll
    for (int r = 0; r < 4; ++r) {
        float l = lsum[r];
        l += __shfl_xor(l, 1, 64); l += __shfl_xor(l, 2, 64);
        l += __shfl_xor(l, 4, 64); l += __shfl_xor(l, 8, 64);
        if (ln == 0)
            Lpart[(size_t)kg * NTOT + bN + q0 + w * 16 + quad * 4 + r] = l;
    }

    // ---- epilogue: Opart via LDS transpose -> coalesced 16B stores.
    // Ps (5120 shorts) is dead after the loop; one 16x264 chunk (4224 shorts)
    // per mt. Each thread then stores 2 bf16x8 = full 512B rows per 32 lanes.
    short* Pst = &Ps[0][0];
    const size_t obase = (size_t)kg * NTOT + bN + q0;
    #pragma unroll
    for (int mt = 0; mt < 4; ++mt) {
        __syncthreads();          // Pst free (last PV / previous chunk reads done)
        #pragma unroll
        for (int nt = 0; nt < 4; ++nt)
            #pragma unroll
            for (int r = 0; r < 4; ++r)
                Pst[(quad * 4 + r) * 264 + wbase + nt * 16 + ln] = f2bf(acc[mt][nt][r]);
        __syncthreads();          // chunk visible block-wide
        #pragma unroll
        for (int i = 0; i < 2; ++i) {
            int idx = tid + i * 256;
            int row = idx >> 5, ch8 = (idx & 31) * 8;
            *(bf16x8*)&Opart[(obase + mt * 16 + row) * 256 + ch8] =
                *(const bf16x8*)&Pst[row * 264 + ch8];
        }
    }
}

// ---------------------------------------------------------------------------
// Kernel 3: mega-fused epilogue. v8 kept (3-region rotation, 6 barriers,
// hoisted input loads, native f2bf).
// ---------------------------------------------------------------------------
__global__ __launch_bounds__(256, 4) void epi_kernel(
    const short* __restrict__ Opart, const float* __restrict__ Lpart,
    const short* __restrict__ W16, const short* __restrict__ Xt16,
    const short* __restrict__ Xn16, const float* __restrict__ mask,
    const float* __restrict__ rs, const float* __restrict__ x,
    float* __restrict__ out)
{
    __shared__ char lds[37696];
    short* Olds  = (short*)lds;              // region A: 16 x 264 (P1-P2)
    short* Clds  = (short*)lds;              // region A reuse (P4-P5)
    short* Dlds  = (short*)(lds + 8448);     // region B: 16 x 528 (P1-P3)
    short* Hlds  = (short*)(lds + 25344);    // region C: 16 x 264 (P3-P4)
    short* tileB = (short*)(lds + 25344);    // region C reuse: 256 x 24 (P5+)
    float* lsh   = (float*)(lds + 37632);    // 16

    const int tid = threadIdx.x;
    const int w = tid >> 6, lane = tid & 63, ln = lane & 15, quad = lane >> 4;
    const int m0 = blockIdx.x * 16;
    const int b = m0 >> 12, p0l = m0 & 4095;

    // ---- hoisted input loads (pure inputs; overlap the barrier drain) ----
    bf16x8 ha0[2], ha1[2], ha2[2], ha3[2], hxn[2];
    float  hmq[2];
    #pragma unroll
    for (int i = 0; i < 2; ++i) {
        int idx = tid + i * 256;
        int q = idx >> 5, ch8 = (idx & 31) * 8;
        size_t base = (size_t)(m0 + q) * 256 + ch8;
        ha0[i] = *(const bf16x8*)&Opart[base];
        ha1[i] = *(const bf16x8*)&Opart[(size_t)NTOT * 256 + base];
        ha2[i] = *(const bf16x8*)&Opart[(size_t)2 * NTOT * 256 + base];
        ha3[i] = *(const bf16x8*)&Opart[(size_t)3 * NTOT * 256 + base];
        hxn[i] = *(const bf16x8*)&Xn16[base];
        hmq[i] = mask[m0 + q];
    }
    short xtv[4][4];
    #pragma unroll
    for (int nt = 0; nt < 4; ++nt)
        #pragma unroll
        for (int r = 0; r < 4; ++r)
            xtv[nt][r] = Xt16[(size_t)(m0 + quad * 4 + r) * 256 + (w * 64 + nt * 16 + ln)];

    if (tid < 16) {
        int g = m0 + tid;
        lsh[tid] = 1.0f / (Lpart[g] + Lpart[NTOT + g] + Lpart[2 * NTOT + g] + Lpart[3 * NTOT + g]);
    }
    __syncthreads();

    // ---- P1: combine partials (from hoisted regs) -> Olds; Xnm -> Dlds ----
    #pragma unroll
    for (int i = 0; i < 2; ++i) {
        int idx = tid + i * 256;
        int q = idx >> 5, ch8 = (idx & 31) * 8;
        float linv = lsh[q];
        bf16x8 o;
        #pragma unroll
        for (int e = 0; e < 8; ++e)
            o[e] = f2bf((bf2f(ha0[i][e]) + bf2f(ha1[i][e]) + bf2f(ha2[i][e]) + bf2f(ha3[i][e])) * linv);
        *(bf16x8*)&Olds[q * 264 + ch8] = o;
        bf16x8 xm;
        #pragma unroll
        for (int e = 0; e < 8; ++e) xm[e] = f2bf(bf2f(hxn[i][e]) * hmq[i]);
        *(bf16x8*)&Dlds[q * 528 + 256 + ch8] = xm;
    }
    __syncthreads();

    // ---- P2: D1 = O@wo^T - Xt (reads A, writes B-lower) ----
    {
        f32x4 acc[4];
        #pragma unroll
        for (int i = 0; i < 4; ++i) acc[i] = (f32x4){0.f, 0.f, 0.f, 0.f};
        #pragma unroll
        for (int kt = 0; kt < 8; ++kt) {
            bf16x8 af = *(const bf16x8*)&Olds[ln * 264 + kt * 32 + quad * 8];
            #pragma unroll
            for (int nt = 0; nt < 4; ++nt) {
                int col = w * 64 + nt * 16 + ln;
                bf16x8 bf = *(const bf16x8*)&W16[OFF_WO + (size_t)col * 256 + kt * 32 + quad * 8];
                acc[nt] = __builtin_amdgcn_mfma_f32_16x16x32_bf16(af, bf, acc[nt], 0, 0, 0);
            }
        }
        #pragma unroll
        for (int nt = 0; nt < 4; ++nt) {
            int col = w * 64 + nt * 16 + ln;
            #pragma unroll
            for (int r = 0; r < 4; ++r) {
                int row = quad * 4 + r;
                float v = acc[nt][r] - bf2f(xtv[nt][r]);
                Dlds[row * 528 + col] = f2bf(v);
            }
        }
    }
    __syncthreads();

    // ---- P3: Hid = gelu([D1|Xnm] @ wd1^T) (reads B, writes C) ----
    {
        f32x4 acc[4];
        #pragma unroll
        for (int i = 0; i < 4; ++i) acc[i] = (f32x4){0.f, 0.f, 0.f, 0.f};
        #pragma unroll
        for (int kt = 0; kt < 16; ++kt) {
            bf16x8 af = *(const bf16x8*)&Dlds[ln * 528 + kt * 32 + quad * 8];
            #pragma unroll
            for (int nt = 0; nt < 4; ++nt) {
                int col = w * 64 + nt * 16 + ln;
                bf16x8 bf = *(const bf16x8*)&W16[OFF_WD1 + (size_t)col * 512 + kt * 32 + quad * 8];
                acc[nt] = __builtin_amdgcn_mfma_f32_16x16x32_bf16(af, bf, acc[nt], 0, 0, 0);
            }
        }
        #pragma unroll
        for (int nt = 0; nt < 4; ++nt) {
            int col = w * 64 + nt * 16 + ln;
            #pragma unroll
            for (int r = 0; r < 4; ++r) {
                int row = quad * 4 + r;
                Hlds[row * 264 + col] = f2bf(gelu_exact(acc[nt][r]));
            }
        }
    }
    __syncthreads();

    // ---- P4: Cor = Hid @ wd2^T (reads C, writes A; A last read in P2) ----
    {
        f32x4 acc[4];
        #pragma unroll
        for (int i = 0; i < 4; ++i) acc[i] = (f32x4){0.f, 0.f, 0.f, 0.f};
        #pragma unroll
        for (int kt = 0; kt < 8; ++kt) {
            bf16x8 af = *(const bf16x8*)&Hlds[ln * 264 + kt * 32 + quad * 8];
            #pragma unroll
            for (int nt = 0; nt < 4; ++nt) {
                int col = w * 64 + nt * 16 + ln;
                bf16x8 bf = *(const bf16x8*)&W16[OFF_WD2 + (size_t)col * 256 + kt * 32 + quad * 8];
                acc[nt] = __builtin_amdgcn_mfma_f32_16x16x32_bf16(af, bf, acc[nt], 0, 0, 0);
            }
        }
        #pragma unroll
        for (int nt = 0; nt < 4; ++nt) {
            int col = w * 64 + nt * 16 + ln;
            #pragma unroll
            for (int r = 0; r < 4; ++r) {
                int row = quad * 4 + r;
                Clds[row * 264 + col] = f2bf(acc[nt][r]);
            }
        }
    }
    __syncthreads();

    // ---- P5: gate GEMM + delta (reads A, writes C; C last read in P4) ----
    {
        f32x4 acc[4];
        #pragma unroll
        for (int i = 0; i < 4; ++i) acc[i] = (f32x4){0.f, 0.f, 0.f, 0.f};
        #pragma unroll
        for (int kt = 0; kt < 8; ++kt) {
            bf16x8 af = *(const bf16x8*)&Clds[ln * 264 + kt * 32 + quad * 8];
            #pragma unroll
            for (int nt = 0; nt < 4; ++nt) {
                int col = w * 64 + nt * 16 + ln;
                bf16x8 bf = *(const bf16x8*)&W16[OFF_WG + (size_t)col * 256 + kt * 32 + quad * 8];
                acc[nt] = __builtin_amdgcn_mfma_f32_16x16x32_bf16(af, bf, acc[nt], 0, 0, 0);
            }
        }
        float trs = tanhf(rs[0]);
        #pragma unroll
        for (int nt = 0; nt < 4; ++nt) {
            int col = w * 64 + nt * 16 + ln;
            float wgl = bf2f(W16[OFF_WGL + col]);
            #pragma unroll
            for (int r = 0; r < 4; ++r) {
                int row = quad * 4 + r;
                float mrow = mask[m0 + row];
                float logit = acc[nt][r] + mrow * wgl;
                float gate = mrow / (1.0f + __expf(-logit));
                float corr = bf2f(Clds[row * 264 + col]);
                tileB[col * 24 + row] = f2bf(trs * gate * corr);
            }
        }
    }
    __syncthreads();

    // ---- store: out[b,ch,p] = x + delta (256 ch x 16 pos) ----
    #pragma unroll
    for (int i = 0; i < 2; ++i) {
        int idx = tid + i * 256;
        int ch = idx >> 1, p8 = (idx & 1) * 8;
        bf16x8 d = *(const bf16x8*)&tileB[ch * 24 + p8];
        size_t o = ((size_t)b * CC + ch) * NN + p0l + p8;
        float4 x0 = *(const float4*)&x[o];
        float4 x1 = *(const float4*)&x[o + 4];
        float4 o0, o1;
        o0.x = x0.x + bf2f(d[0]); o0.y = x0.y + bf2f(d[1]);
        o0.z = x0.z + bf2f(d[2]); o0.w = x0.w + bf2f(d[3]);
        o1.x = x1.x + bf2f(d[4]); o1.y = x1.y + bf2f(d[5]);
        o1.z = x1.z + bf2f(d[6]); o1.w = x1.w + bf2f(d[7]);
        *(float4*)&out[o] = o0;
        *(float4*)&out[o + 4] = o1;
    }
}

// ---------------------------------------------------------------------------
extern "C" void kernel_launch(void* const* d_in, const int* in_sizes, int n_in,
                              void* d_out, int out_size, void* d_ws, size_t ws_size,
                              hipStream_t stream) {
    const float* x     = (const float*)d_in[0];
    const float* mask  = (const float*)d_in[1];
    const float* gamma = (const float*)d_in[2];
    const float* beta  = (const float*)d_in[3];
    const float* wq    = (const float*)d_in[4];
    const float* wk    = (const float*)d_in[5];
    const float* wv    = (const float*)d_in[6];
    const float* w_out = (const float*)d_in[7];
    const float* w_qm  = (const float*)d_in[8];
    const float* wd1   = (const float*)d_in[9];
    const float* wd2   = (const float*)d_in[10];
    const float* wg    = (const float*)d_in[11];
    const float* rs    = (const float*)d_in[12];
    float* out = (float*)d_out;

    const size_t NC = (size_t)NTOT * CC;
    const size_t NE = (size_t)NTOT * EE;
    short* Xn16  = (short*)d_ws;        // NC
    short* Xt16  = Xn16 + NC;           // NC
    short* Q16   = Xt16 + NC;           // NE
    short* K16   = Q16 + NE;            // NE
    short* V16t  = K16 + NE;            // NC
    short* W16   = V16t + NC;           // W16_TOTAL
    short* Opart = W16 + W16_TOTAL;     // 4*NC
    float* Lpart = (float*)(Opart + 4 * NC);   // 4*NTOT f32
    // ~66 MB total

    wconv_kernel<<<(W16_TOTAL / 4 + 255) / 256, 256, 0, stream>>>(wq, wk, wv, w_out,
                                                                  wd1, wd2, wg, W16);
    lnproj_kernel<<<1024, 256, 0, stream>>>(x, gamma, beta, W16, mask, w_qm,
                                            Xt16, Xn16, Q16, K16, V16t);
    attn_kernel<<<1024, 256, 0, stream>>>(Q16, K16, V16t, mask, Opart, Lpart);
    epi_kernel<<<1024, 256, 0, stream>>>(Opart, Lpart, W16, Xt16, Xn16, mask,
                                         rs, x, out);
}